// Round 1
// baseline (792.379 us; speedup 1.0000x reference)
//
#include <hip/hip_runtime.h>
#include <hip/hip_bf16.h>

// GCN 2-layer: xw=x@W; out[v]=dinv[v]*(sum_{e:dst=v} dinv[src]*xw[src] + dinv[v]*xw[v]) + b
// Layer1: relu. Layer2: no relu, D_out=70.
// CSR (sorted by dst) rebuilt every call from edge_index in d_ws.

#define N_NODES 100000
#define N_EDGES 1600000
#define SCAN_B 256

__global__ void k_count_deg(const int* __restrict__ dst, int* __restrict__ deg, int E) {
    int i = blockIdx.x * blockDim.x + threadIdx.x;
    int stride = gridDim.x * blockDim.x;
    for (; i < E; i += stride) atomicAdd(&deg[dst[i]], 1);
}

__global__ void k_dinv(const int* __restrict__ deg, float* __restrict__ dinv, int n) {
    int i = blockIdx.x * blockDim.x + threadIdx.x;
    if (i < n) dinv[i] = rsqrtf((float)(deg[i] + 1));  // +1 self-loop
}

__global__ void k_scan_blocks(const int* __restrict__ deg, int* __restrict__ rs,
                              int* __restrict__ blksum, int n) {
    __shared__ int s[SCAN_B];
    int t = threadIdx.x;
    int i = blockIdx.x * SCAN_B + t;
    int v = (i < n) ? deg[i] : 0;
    s[t] = v;
    __syncthreads();
    for (int off = 1; off < SCAN_B; off <<= 1) {
        int add = (t >= off) ? s[t - off] : 0;
        __syncthreads();
        s[t] += add;
        __syncthreads();
    }
    if (i < n) rs[i] = s[t] - v;  // exclusive
    if (t == SCAN_B - 1) blksum[blockIdx.x] = s[t];
}

__global__ void k_scan_totals(int* __restrict__ blksum, int nblk) {
    __shared__ int s[512];
    int t = threadIdx.x;
    int v = (t < nblk) ? blksum[t] : 0;
    s[t] = v;
    __syncthreads();
    for (int off = 1; off < 512; off <<= 1) {
        int add = (t >= off) ? s[t - off] : 0;
        __syncthreads();
        s[t] += add;
        __syncthreads();
    }
    if (t < nblk) blksum[t] = s[t] - v;  // exclusive
}

__global__ void k_add_offsets(int* __restrict__ rs, int* __restrict__ cursor,
                              const int* __restrict__ blksum, int n) {
    int i = blockIdx.x * blockDim.x + threadIdx.x;
    if (i < n) {
        int r = rs[i] + blksum[i / SCAN_B];
        rs[i] = r;
        cursor[i] = r;
    }
}

__global__ void k_scatter(const int* __restrict__ src, const int* __restrict__ dst,
                          int* __restrict__ cursor, int* __restrict__ csr, int E) {
    int i = blockIdx.x * blockDim.x + threadIdx.x;
    int stride = gridDim.x * blockDim.x;
    for (; i < E; i += stride) {
        int p = atomicAdd(&cursor[dst[i]], 1);
        csr[p] = src[i];
    }
}

// Simple fp32 GEMM: Y[n,DOUT] = X[n,K] @ W[K,DOUT]. ROWS rows per 128-thread block.
template <int ROWS, int K, int DOUT>
__global__ void k_gemm(const float* __restrict__ X, const float* __restrict__ W,
                       float* __restrict__ Y, int n) {
    __shared__ float xs[ROWS][K];
    int r0 = blockIdx.x * ROWS;
    int t = threadIdx.x;  // 128
    for (int idx = t; idx < ROWS * K; idx += 128) {
        int r = idx / K, k = idx % K;
        int gr = r0 + r;
        xs[r][k] = (gr < n) ? X[gr * K + k] : 0.f;
    }
    __syncthreads();
    if (t < DOUT) {
        float acc[ROWS];
#pragma unroll
        for (int r = 0; r < ROWS; r++) acc[r] = 0.f;
        for (int k = 0; k < K; k++) {
            float w = W[k * DOUT + t];
#pragma unroll
            for (int r = 0; r < ROWS; r++) acc[r] += xs[r][k] * w;
        }
#pragma unroll
        for (int r = 0; r < ROWS; r++) {
            int gr = r0 + r;
            if (gr < n) Y[gr * DOUT + t] = acc[r];
        }
    }
}

// One block (128 threads) per node; d = threadIdx.x < D.
template <int D>
__global__ void k_agg(const float* __restrict__ xw, const float* __restrict__ dinv,
                      const int* __restrict__ rs, const int* __restrict__ deg,
                      const int* __restrict__ csr, const float* __restrict__ bias,
                      float* __restrict__ out, int n, int relu) {
    int v = blockIdx.x;
    if (v >= n) return;
    int d = threadIdx.x;
    if (d >= D) return;
    float dv = dinv[v];
    int start = rs[v];
    int cnt = deg[v];
    float acc = 0.f;
    for (int i = 0; i < cnt; i++) {
        int s = csr[start + i];
        acc += dinv[s] * xw[s * D + d];
    }
    acc += dv * xw[v * D + d];  // self-loop
    acc = dv * acc + bias[d];
    if (relu) acc = fmaxf(acc, 0.f);
    out[v * D + d] = acc;
}

static inline size_t alignup(size_t x) { return (x + 255) & ~(size_t)255; }

extern "C" void kernel_launch(void* const* d_in, const int* in_sizes, int n_in,
                              void* d_out, int out_size, void* d_ws, size_t ws_size,
                              hipStream_t stream) {
    const float* x = (const float*)d_in[0];
    const int* edge = (const int*)d_in[1];
    const float* W1 = (const float*)d_in[2];
    const float* b1 = (const float*)d_in[3];
    const float* W2 = (const float*)d_in[4];
    const float* b2 = (const float*)d_in[5];

    const int N = in_sizes[0] / 128;
    const int E = in_sizes[1] / 2;
    const int* src = edge;
    const int* dst = edge + E;

    char* w = (char*)d_ws;
    int* deg = (int*)w;        w += alignup((size_t)N * 4);
    float* dinv = (float*)w;   w += alignup((size_t)N * 4);
    int* rs = (int*)w;         w += alignup((size_t)N * 4);
    int* cursor = (int*)w;     w += alignup((size_t)N * 4);
    int* blksum = (int*)w;     w += alignup(4096);
    int* csr = (int*)w;        w += alignup((size_t)E * 4);
    float* bufA = (float*)w;   w += alignup((size_t)N * 128 * 4);
    float* bufB = (float*)w;   w += alignup((size_t)N * 128 * 4);

    int nblk = (N + SCAN_B - 1) / SCAN_B;  // 391 for N=100000

    hipMemsetAsync(deg, 0, (size_t)N * 4, stream);
    k_count_deg<<<2048, 256, 0, stream>>>(dst, deg, E);
    k_dinv<<<(N + 255) / 256, 256, 0, stream>>>(deg, dinv, N);
    k_scan_blocks<<<nblk, SCAN_B, 0, stream>>>(deg, rs, blksum, N);
    k_scan_totals<<<1, 512, 0, stream>>>(blksum, nblk);
    k_add_offsets<<<(N + 255) / 256, 256, 0, stream>>>(rs, cursor, blksum, N);
    k_scatter<<<2048, 256, 0, stream>>>(src, dst, cursor, csr, E);

    // Layer 1: xw1 = x @ W1 -> bufA ; agg -> bufB (bias+relu)
    k_gemm<8, 128, 128><<<(N + 7) / 8, 128, 0, stream>>>(x, W1, bufA, N);
    k_agg<128><<<N, 128, 0, stream>>>(bufA, dinv, rs, deg, csr, b1, bufB, N, 1);

    // Layer 2: hw2 = bufB @ W2 -> bufA ; agg -> d_out (bias, no relu)
    k_gemm<8, 128, 70><<<(N + 7) / 8, 128, 0, stream>>>(bufB, W2, bufA, N);
    k_agg<70><<<N, 128, 0, stream>>>(bufA, dinv, rs, deg, csr, b2, (float*)d_out, N, 0);
}

// Round 2
// 666.844 us; speedup vs baseline: 1.1883x; 1.1883x over previous
//
#include <hip/hip_runtime.h>
#include <hip/hip_bf16.h>

// GCN 2-layer: xw=x@W; out[v]=dinv[v]*(sum_{e:dst=v} dinv[src]*xw[src] + dinv[v]*xw[v]) + b
// Layer1: relu, D=128. Layer2: no relu, D=70 (xw padded to stride 72 for float4 gathers).
// CSR (sorted by dst) rebuilt every call from edge_index in d_ws.

#define SCAN_B 256

__global__ void k_count_deg(const int* __restrict__ dst, int* __restrict__ deg, int E) {
    int i = blockIdx.x * blockDim.x + threadIdx.x;
    int stride = gridDim.x * blockDim.x;
    for (; i < E; i += stride) atomicAdd(&deg[dst[i]], 1);
}

__global__ void k_dinv(const int* __restrict__ deg, float* __restrict__ dinv, int n) {
    int i = blockIdx.x * blockDim.x + threadIdx.x;
    if (i < n) dinv[i] = rsqrtf((float)(deg[i] + 1));  // +1 self-loop
}

__global__ void k_scan_blocks(const int* __restrict__ deg, int* __restrict__ rs,
                              int* __restrict__ blksum, int n) {
    __shared__ int s[SCAN_B];
    int t = threadIdx.x;
    int i = blockIdx.x * SCAN_B + t;
    int v = (i < n) ? deg[i] : 0;
    s[t] = v;
    __syncthreads();
    for (int off = 1; off < SCAN_B; off <<= 1) {
        int add = (t >= off) ? s[t - off] : 0;
        __syncthreads();
        s[t] += add;
        __syncthreads();
    }
    if (i < n) rs[i] = s[t] - v;  // exclusive
    if (t == SCAN_B - 1) blksum[blockIdx.x] = s[t];
}

__global__ void k_scan_totals(int* __restrict__ blksum, int nblk) {
    __shared__ int s[512];
    int t = threadIdx.x;
    int v = (t < nblk) ? blksum[t] : 0;
    s[t] = v;
    __syncthreads();
    for (int off = 1; off < 512; off <<= 1) {
        int add = (t >= off) ? s[t - off] : 0;
        __syncthreads();
        s[t] += add;
        __syncthreads();
    }
    if (t < nblk) blksum[t] = s[t] - v;  // exclusive
}

__global__ void k_add_offsets(int* __restrict__ rs, int* __restrict__ cursor,
                              const int* __restrict__ blksum, int n) {
    int i = blockIdx.x * blockDim.x + threadIdx.x;
    if (i < n) {
        int r = rs[i] + blksum[i / SCAN_B];
        rs[i] = r;
        cursor[i] = r;
    }
}

__global__ void k_scatter(const int* __restrict__ src, const int* __restrict__ dst,
                          int* __restrict__ cursor, int* __restrict__ csr, int E) {
    int i = blockIdx.x * blockDim.x + threadIdx.x;
    int stride = gridDim.x * blockDim.x;
    for (; i < E; i += stride) {
        int p = atomicAdd(&cursor[dst[i]], 1);
        csr[p] = src[i];
    }
}

// fp32 GEMM: Y[n,*STRIDE*] = X[n,K] @ W[K,DOUT]; cols [DOUT,STRIDE) zero-padded.
template <int ROWS, int K, int DOUT, int STRIDE>
__global__ void k_gemm(const float* __restrict__ X, const float* __restrict__ W,
                       float* __restrict__ Y, int n) {
    __shared__ float xs[ROWS][K];
    int r0 = blockIdx.x * ROWS;
    int t = threadIdx.x;  // 128
    for (int idx = t; idx < ROWS * K; idx += 128) {
        int r = idx / K, k = idx % K;
        int gr = r0 + r;
        xs[r][k] = (gr < n) ? X[gr * K + k] : 0.f;
    }
    __syncthreads();
    if (t < DOUT) {
        float acc[ROWS];
#pragma unroll
        for (int r = 0; r < ROWS; r++) acc[r] = 0.f;
        for (int k = 0; k < K; k++) {
            float w = W[k * DOUT + t];
#pragma unroll
            for (int r = 0; r < ROWS; r++) acc[r] += xs[r][k] * w;
        }
#pragma unroll
        for (int r = 0; r < ROWS; r++) {
            int gr = r0 + r;
            if (gr < n) Y[(size_t)gr * STRIDE + t] = acc[r];
        }
    } else if (t < STRIDE) {
#pragma unroll
        for (int r = 0; r < ROWS; r++) {
            int gr = r0 + r;
            if (gr < n) Y[(size_t)gr * STRIDE + t] = 0.f;
        }
    }
}

// Vectorized aggregation: SLOTS edges in flight per block, float4 gathers.
// xw has row stride DSTRIDE floats (DSTRIDE%4==0); TPR = DSTRIDE/4 threads per row.
// out has dense row stride D (scalar stores handle D%4 != 0).
template <int D, int DSTRIDE, int SLOTS, int RELU>
__global__ void k_agg_v(const float* __restrict__ xw, const float* __restrict__ dinv,
                        const int* __restrict__ rs, const int* __restrict__ deg,
                        const int* __restrict__ csr, const float* __restrict__ bias,
                        float* __restrict__ out, int n) {
    constexpr int TPR = DSTRIDE / 4;
    constexpr int ACTIVE = SLOTS * TPR;
    __shared__ float4 red[SLOTS][TPR];
    int v = blockIdx.x;
    if (v >= n) return;
    int t = threadIdx.x;
    int slot = t / TPR;
    int q = t - slot * TPR;
    int start = rs[v];
    int cnt = deg[v];
    const float4* xw4 = (const float4*)xw;
    if (t < ACTIVE) {
        float4 acc = {0.f, 0.f, 0.f, 0.f};
        for (int i = slot; i < cnt; i += SLOTS) {
            int s = csr[start + i];
            float a = dinv[s];
            float4 m = xw4[(size_t)s * TPR + q];
            acc.x += a * m.x;
            acc.y += a * m.y;
            acc.z += a * m.z;
            acc.w += a * m.w;
        }
        red[slot][q] = acc;
    }
    __syncthreads();
    if (t < TPR) {
        float4 sum = red[0][t];
#pragma unroll
        for (int s2 = 1; s2 < SLOTS; s2++) {
            float4 r = red[s2][t];
            sum.x += r.x;
            sum.y += r.y;
            sum.z += r.z;
            sum.w += r.w;
        }
        float dv = dinv[v];
        float4 self = xw4[(size_t)v * TPR + t];
        sum.x += dv * self.x;
        sum.y += dv * self.y;
        sum.z += dv * self.z;
        sum.w += dv * self.w;
        float o[4] = {sum.x, sum.y, sum.z, sum.w};
#pragma unroll
        for (int j = 0; j < 4; j++) {
            int f = 4 * t + j;
            if (f < D) {
                float r = dv * o[j] + bias[f];
                if (RELU) r = fmaxf(r, 0.f);
                out[(size_t)v * D + f] = r;
            }
        }
    }
}

static inline size_t alignup(size_t x) { return (x + 255) & ~(size_t)255; }

extern "C" void kernel_launch(void* const* d_in, const int* in_sizes, int n_in,
                              void* d_out, int out_size, void* d_ws, size_t ws_size,
                              hipStream_t stream) {
    const float* x = (const float*)d_in[0];
    const int* edge = (const int*)d_in[1];
    const float* W1 = (const float*)d_in[2];
    const float* b1 = (const float*)d_in[3];
    const float* W2 = (const float*)d_in[4];
    const float* b2 = (const float*)d_in[5];

    const int N = in_sizes[0] / 128;
    const int E = in_sizes[1] / 2;
    const int* src = edge;
    const int* dst = edge + E;

    char* w = (char*)d_ws;
    int* deg = (int*)w;        w += alignup((size_t)N * 4);
    float* dinv = (float*)w;   w += alignup((size_t)N * 4);
    int* rs = (int*)w;         w += alignup((size_t)N * 4);
    int* cursor = (int*)w;     w += alignup((size_t)N * 4);
    int* blksum = (int*)w;     w += alignup(4096);
    int* csr = (int*)w;        w += alignup((size_t)E * 4);
    float* bufA = (float*)w;   w += alignup((size_t)N * 128 * 4);
    float* bufB = (float*)w;   w += alignup((size_t)N * 128 * 4);

    int nblk = (N + SCAN_B - 1) / SCAN_B;  // 391 for N=100000

    hipMemsetAsync(deg, 0, (size_t)N * 4, stream);
    k_count_deg<<<2048, 256, 0, stream>>>(dst, deg, E);
    k_dinv<<<(N + 255) / 256, 256, 0, stream>>>(deg, dinv, N);
    k_scan_blocks<<<nblk, SCAN_B, 0, stream>>>(deg, rs, blksum, N);
    k_scan_totals<<<1, 512, 0, stream>>>(blksum, nblk);
    k_add_offsets<<<(N + 255) / 256, 256, 0, stream>>>(rs, cursor, blksum, N);
    k_scatter<<<2048, 256, 0, stream>>>(src, dst, cursor, csr, E);

    // Layer 1: xw1 = x @ W1 -> bufA [N,128] ; agg -> bufB [N,128] (bias+relu)
    k_gemm<8, 128, 128, 128><<<(N + 7) / 8, 128, 0, stream>>>(x, W1, bufA, N);
    k_agg_v<128, 128, 8, 1><<<N, 256, 0, stream>>>(bufA, dinv, rs, deg, csr, b1, bufB, N);

    // Layer 2: hw2 = bufB @ W2 -> bufA [N,72 padded] ; agg -> d_out [N,70]
    k_gemm<8, 128, 70, 72><<<(N + 7) / 8, 128, 0, stream>>>(bufB, W2, bufA, N);
    k_agg_v<70, 72, 7, 0><<<N, 128, 0, stream>>>(bufA, dinv, rs, deg, csr, b2, (float*)d_out, N);
}

// Round 3
// 649.406 us; speedup vs baseline: 1.2202x; 1.0269x over previous
//
#include <hip/hip_runtime.h>
#include <hip/hip_bf16.h>

// GCN 2-layer. msg[s] = dinv[s] * (x@W)[s] stored in bf16 (dinv folded at GEMM epilogue).
// out[v] = dinv[v] * (sum_{e:dst=v} msg[src] + msg[v]) + b ; layer1 relu.
// Layer1 msgs: [N,128] bf16 (16 uint4 chunks/row). Layer2: [N,72] bf16 (9 chunks, 70 valid).
// CSR (sorted by dst) rebuilt every call in d_ws.

#define SCAN_B 256

__device__ __forceinline__ float bf_lo(unsigned u) { return __uint_as_float(u << 16); }
__device__ __forceinline__ float bf_hi(unsigned u) { return __uint_as_float(u & 0xffff0000u); }
__device__ __forceinline__ unsigned short f2bf(float f) {
    unsigned u = __float_as_uint(f);
    u += 0x7fff + ((u >> 16) & 1);  // round-to-nearest-even
    return (unsigned short)(u >> 16);
}

__global__ void k_count_deg(const int* __restrict__ dst, int* __restrict__ deg, int E) {
    int i = blockIdx.x * blockDim.x + threadIdx.x;
    int stride = gridDim.x * blockDim.x;
    for (; i < E; i += stride) atomicAdd(&deg[dst[i]], 1);
}

__global__ void k_scan_blocks(const int* __restrict__ deg, int* __restrict__ rs,
                              int* __restrict__ blksum, int n) {
    __shared__ int s[SCAN_B];
    int t = threadIdx.x;
    int i = blockIdx.x * SCAN_B + t;
    int v = (i < n) ? deg[i] : 0;
    s[t] = v;
    __syncthreads();
    for (int off = 1; off < SCAN_B; off <<= 1) {
        int add = (t >= off) ? s[t - off] : 0;
        __syncthreads();
        s[t] += add;
        __syncthreads();
    }
    if (i < n) rs[i] = s[t] - v;  // exclusive
    if (t == SCAN_B - 1) blksum[blockIdx.x] = s[t];
}

__global__ void k_scan_totals(int* __restrict__ blksum, int nblk) {
    __shared__ int s[512];
    int t = threadIdx.x;
    int v = (t < nblk) ? blksum[t] : 0;
    s[t] = v;
    __syncthreads();
    for (int off = 1; off < 512; off <<= 1) {
        int add = (t >= off) ? s[t - off] : 0;
        __syncthreads();
        s[t] += add;
        __syncthreads();
    }
    if (t < nblk) blksum[t] = s[t] - v;  // exclusive
}

__global__ void k_add_offsets(int* __restrict__ rs, int* __restrict__ cursor,
                              const int* __restrict__ blksum, const int* __restrict__ deg,
                              float* __restrict__ dinv, int n) {
    int i = blockIdx.x * blockDim.x + threadIdx.x;
    if (i < n) {
        int r = rs[i] + blksum[i / SCAN_B];
        rs[i] = r;
        cursor[i] = r;
        dinv[i] = rsqrtf((float)(deg[i] + 1));  // +1 self-loop
    }
}

__global__ void k_scatter(const int* __restrict__ src, const int* __restrict__ dst,
                          int* __restrict__ cursor, int* __restrict__ csr, int E) {
    int i = blockIdx.x * blockDim.x + threadIdx.x;
    int stride = gridDim.x * blockDim.x;
    for (; i < E; i += stride) {
        int p = atomicAdd(&cursor[dst[i]], 1);
        csr[p] = src[i];
    }
}

// fp32 GEMM, bf16 output scaled by dinv[row]: Y[r, t] = bf16(dinv[r] * (X@W)[r, t]).
// Columns [DOUT, OSTRIDE) zero-padded. Block = 128 threads, ROWS rows per block.
template <int ROWS, int K, int DOUT, int OSTRIDE>
__global__ void k_gemm_bf(const float* __restrict__ X, const float* __restrict__ W,
                          const float* __restrict__ dinv, unsigned short* __restrict__ Y,
                          int n) {
    __shared__ float xs[ROWS][K];
    int r0 = blockIdx.x * ROWS;
    int t = threadIdx.x;  // 128
    for (int idx = t; idx < ROWS * K; idx += 128) {
        int r = idx / K, k = idx - r * K;
        int gr = r0 + r;
        xs[r][k] = (gr < n) ? X[(size_t)gr * K + k] : 0.f;
    }
    __syncthreads();
    if (t < OSTRIDE) {
        float acc[ROWS];
#pragma unroll
        for (int r = 0; r < ROWS; r++) acc[r] = 0.f;
        if (t < DOUT) {
            for (int k = 0; k < K; k++) {
                float w = W[k * DOUT + t];
#pragma unroll
                for (int r = 0; r < ROWS; r++) acc[r] += xs[r][k] * w;
            }
        }
#pragma unroll
        for (int r = 0; r < ROWS; r++) {
            int gr = r0 + r;
            if (gr < n) Y[(size_t)gr * OSTRIDE + t] = f2bf(acc[r] * dinv[gr]);
        }
    }
}

// bf16-message aggregation. msg rows = TPR uint4 chunks (8 bf16 each).
// SLOTS edges in flight per block; fp32 accumulate; LDS tree-reduce over slots.
template <int TPR, int SLOTS, int D, int RELU>
__global__ void k_agg_bf(const uint4* __restrict__ msg, const float* __restrict__ dinv,
                         const int* __restrict__ rs, const int* __restrict__ deg,
                         const int* __restrict__ csr, const float* __restrict__ bias,
                         float* __restrict__ out, int n) {
    __shared__ float red[SLOTS][TPR][8];
    int v = blockIdx.x;
    if (v >= n) return;
    int t = threadIdx.x;
    int slot = t / TPR;
    int q = t - slot * TPR;
    int start = rs[v];
    int cnt = deg[v];
    if (slot < SLOTS) {
        float acc[8] = {0.f, 0.f, 0.f, 0.f, 0.f, 0.f, 0.f, 0.f};
        for (int i = slot; i < cnt; i += SLOTS) {
            int s = csr[start + i];
            uint4 m = msg[(size_t)s * TPR + q];
            acc[0] += bf_lo(m.x); acc[1] += bf_hi(m.x);
            acc[2] += bf_lo(m.y); acc[3] += bf_hi(m.y);
            acc[4] += bf_lo(m.z); acc[5] += bf_hi(m.z);
            acc[6] += bf_lo(m.w); acc[7] += bf_hi(m.w);
        }
#pragma unroll
        for (int j = 0; j < 8; j++) red[slot][q][j] = acc[j];
    }
    __syncthreads();
#pragma unroll
    for (int sh = SLOTS / 2; sh >= 1; sh >>= 1) {
        if (slot < sh) {
#pragma unroll
            for (int j = 0; j < 8; j++) red[slot][q][j] += red[slot + sh][q][j];
        }
        __syncthreads();
    }
    if (t < TPR) {
        float dv = dinv[v];
        uint4 m = msg[(size_t)v * TPR + t];  // self-loop: msg[v] = dv*xw[v]
        float o[8];
        o[0] = red[0][t][0] + bf_lo(m.x); o[1] = red[0][t][1] + bf_hi(m.x);
        o[2] = red[0][t][2] + bf_lo(m.y); o[3] = red[0][t][3] + bf_hi(m.y);
        o[4] = red[0][t][4] + bf_lo(m.z); o[5] = red[0][t][5] + bf_hi(m.z);
        o[6] = red[0][t][6] + bf_lo(m.w); o[7] = red[0][t][7] + bf_hi(m.w);
#pragma unroll
        for (int j = 0; j < 8; j++) {
            int f = 8 * t + j;
            if (f < D) {
                float r = dv * o[j] + bias[f];
                if (RELU) r = fmaxf(r, 0.f);
                out[(size_t)v * D + f] = r;
            }
        }
    }
}

static inline size_t alignup(size_t x) { return (x + 255) & ~(size_t)255; }

extern "C" void kernel_launch(void* const* d_in, const int* in_sizes, int n_in,
                              void* d_out, int out_size, void* d_ws, size_t ws_size,
                              hipStream_t stream) {
    const float* x = (const float*)d_in[0];
    const int* edge = (const int*)d_in[1];
    const float* W1 = (const float*)d_in[2];
    const float* b1 = (const float*)d_in[3];
    const float* W2 = (const float*)d_in[4];
    const float* b2 = (const float*)d_in[5];

    const int N = in_sizes[0] / 128;
    const int E = in_sizes[1] / 2;
    const int* src = edge;
    const int* dst = edge + E;

    char* w = (char*)d_ws;
    int* deg = (int*)w;              w += alignup((size_t)N * 4);
    float* dinv = (float*)w;         w += alignup((size_t)N * 4);
    int* rs = (int*)w;               w += alignup((size_t)N * 4);
    int* cursor = (int*)w;           w += alignup((size_t)N * 4);
    int* blksum = (int*)w;           w += alignup(4096);
    int* csr = (int*)w;              w += alignup((size_t)E * 4);
    unsigned short* msg1 = (unsigned short*)w; w += alignup((size_t)N * 128 * 2);
    unsigned short* msg2 = (unsigned short*)w; w += alignup((size_t)N * 72 * 2);
    float* h = (float*)w;            w += alignup((size_t)N * 128 * 4);

    int nblk = (N + SCAN_B - 1) / SCAN_B;

    hipMemsetAsync(deg, 0, (size_t)N * 4, stream);
    k_count_deg<<<2048, 256, 0, stream>>>(dst, deg, E);
    k_scan_blocks<<<nblk, SCAN_B, 0, stream>>>(deg, rs, blksum, N);
    k_scan_totals<<<1, 512, 0, stream>>>(blksum, nblk);
    k_add_offsets<<<(N + 255) / 256, 256, 0, stream>>>(rs, cursor, blksum, deg, dinv, N);
    k_scatter<<<2048, 256, 0, stream>>>(src, dst, cursor, csr, E);

    // Layer 1: msg1 = bf16(dinv * (x @ W1)) [N,128] ; agg -> h [N,128] fp32 (bias+relu)
    k_gemm_bf<8, 128, 128, 128><<<(N + 7) / 8, 128, 0, stream>>>(x, W1, dinv, msg1, N);
    k_agg_bf<16, 16, 128, 1><<<N, 256, 0, stream>>>((const uint4*)msg1, dinv, rs, deg, csr,
                                                    b1, h, N);

    // Layer 2: msg2 = bf16(dinv * (h @ W2)) [N,72 pad] ; agg -> d_out [N,70] (bias)
    k_gemm_bf<8, 128, 70, 72><<<(N + 7) / 8, 128, 0, stream>>>(h, W2, dinv, msg2, N);
    k_agg_bf<9, 16, 70, 0><<<N, 192, 0, stream>>>((const uint4*)msg2, dinv, rs, deg, csr,
                                                  b2, (float*)d_out, N);
}

// Round 4
// 525.424 us; speedup vs baseline: 1.5081x; 1.2360x over previous
//
#include <hip/hip_runtime.h>
#include <hip/hip_bf16.h>

// GCN 2-layer. msg[s] = dinv[s] * (x@W)[s] stored in bf16 (dinv folded at GEMM epilogue).
// out[v] = dinv[v] * (sum_{e:dst=v} msg[src] + msg[v]) + b ; layer1 relu.
// CSR build: bucketed 2-phase counting sort (bucket = dst>>8, W=256 nodes/bucket).
//   Pass B groups edges by bucket with per-block LDS runs (dense 8B writes).
//   Pass C (1 block/bucket): LDS per-node count + scan -> deg/dinv/rs dense,
//   csr scatter confined to one 16KB window per block (one XCD -> full-line writeback).

#define BSH 8           // bucket shift: 256 nodes per bucket
#define BCHUNK 8192     // edges per pass-B block

__device__ __forceinline__ float bf_lo(unsigned u) { return __uint_as_float(u << 16); }
__device__ __forceinline__ float bf_hi(unsigned u) { return __uint_as_float(u & 0xffff0000u); }
__device__ __forceinline__ unsigned short f2bf(float f) {
    unsigned u = __float_as_uint(f);
    u += 0x7fff + ((u >> 16) & 1);  // round-to-nearest-even
    return (unsigned short)(u >> 16);
}

// Bucket histogram over dst (LDS-staged).
__global__ void k_bucket_hist(const int* __restrict__ dst, int* __restrict__ bhist,
                              int E, int nb) {
    __shared__ int h[512];
    int t = threadIdx.x;
    for (int j = t; j < nb; j += blockDim.x) h[j] = 0;
    __syncthreads();
    int i = blockIdx.x * blockDim.x + t;
    int stride = gridDim.x * blockDim.x;
    for (; i < E; i += stride) atomicAdd(&h[dst[i] >> BSH], 1);
    __syncthreads();
    for (int j = t; j < nb; j += blockDim.x) {
        int c = h[j];
        if (c) atomicAdd(&bhist[j], c);
    }
}

// Exclusive scan of bucket counts (nb <= 512), one block of 512.
__global__ void k_bucket_scan(const int* __restrict__ bhist, int* __restrict__ bbase,
                              int* __restrict__ bwcur, int nb, int E) {
    __shared__ int s[512];
    int t = threadIdx.x;
    int v = (t < nb) ? bhist[t] : 0;
    s[t] = v;
    __syncthreads();
    for (int off = 1; off < 512; off <<= 1) {
        int add = (t >= off) ? s[t - off] : 0;
        __syncthreads();
        s[t] += add;
        __syncthreads();
    }
    if (t < nb) {
        int excl = s[t] - v;
        bbase[t] = excl;
        bwcur[t] = excl;
    }
    if (t == 0) bbase[nb] = E;
}

// Pass B: group edges by bucket into tmp (packed dst<<32|src), per-block runs.
__global__ void k_bucket_scatter(const int* __restrict__ src, const int* __restrict__ dst,
                                 int* __restrict__ bwcur,
                                 unsigned long long* __restrict__ tmp, int E, int nb) {
    __shared__ int lh[512];   // per-block bucket counts, then per-bucket running offset
    __shared__ int lb[512];   // per-block bucket base in tmp
    int t = threadIdx.x;
    for (int j = t; j < nb; j += 256) lh[j] = 0;
    __syncthreads();
    int e0 = blockIdx.x * BCHUNK;
    int e1 = min(E, e0 + BCHUNK);
    for (int e = e0 + t; e < e1; e += 256) atomicAdd(&lh[dst[e] >> BSH], 1);
    __syncthreads();
    for (int j = t; j < nb; j += 256) {
        int c = lh[j];
        lb[j] = c ? atomicAdd(&bwcur[j], c) : 0;
        lh[j] = 0;
    }
    __syncthreads();
    for (int e = e0 + t; e < e1; e += 256) {
        int d = dst[e];
        int b = d >> BSH;
        int o = atomicAdd(&lh[b], 1);
        tmp[lb[b] + o] = ((unsigned long long)(unsigned)d << 32) | (unsigned)src[e];
    }
}

// Pass C: one block per bucket. Per-node degree count (LDS), scan, write
// deg/dinv/rs densely, scatter csr within this bucket's window (LDS cursors).
__global__ void k_bucket_finalize(const unsigned long long* __restrict__ tmp,
                                  const int* __restrict__ bbase,
                                  int* __restrict__ deg, float* __restrict__ dinv,
                                  int* __restrict__ rs, int* __restrict__ csr, int N) {
    __shared__ int cnt[256];  // per-node count, later reused as cursor
    __shared__ int sc[256];   // scan buffer -> exclusive prefix
    int b = blockIdx.x;
    int t = threadIdx.x;
    int e0 = bbase[b], e1 = bbase[b + 1];
    cnt[t] = 0;
    __syncthreads();
    for (int e = e0 + t; e < e1; e += 256) {
        int d = (int)(tmp[e] >> 32);
        atomicAdd(&cnt[d & 255], 1);
    }
    __syncthreads();
    int c = cnt[t];
    sc[t] = c;
    __syncthreads();
    for (int off = 1; off < 256; off <<= 1) {
        int add = (t >= off) ? sc[t - off] : 0;
        __syncthreads();
        sc[t] += add;
        __syncthreads();
    }
    int excl = sc[t] - c;
    __syncthreads();
    sc[t] = excl;  // exclusive prefix, needed by all threads below
    int node = (b << BSH) + t;
    if (node < N) {
        deg[node] = c;
        dinv[node] = rsqrtf((float)(c + 1));  // +1 self-loop
        rs[node] = e0 + excl;
    }
    cnt[t] = 0;  // cursor
    __syncthreads();
    for (int e = e0 + t; e < e1; e += 256) {
        unsigned long long p = tmp[e];
        int j = ((int)(p >> 32)) & 255;
        int o = atomicAdd(&cnt[j], 1);
        csr[e0 + sc[j] + o] = (int)(p & 0xffffffffu);
    }
}

// fp32 GEMM, bf16 output scaled by dinv[row]: Y[r, t] = bf16(dinv[r] * (X@W)[r, t]).
// Columns [DOUT, OSTRIDE) zero-padded. Block = 128 threads, ROWS rows per block.
template <int ROWS, int K, int DOUT, int OSTRIDE>
__global__ void k_gemm_bf(const float* __restrict__ X, const float* __restrict__ W,
                          const float* __restrict__ dinv, unsigned short* __restrict__ Y,
                          int n) {
    __shared__ float xs[ROWS][K];
    int r0 = blockIdx.x * ROWS;
    int t = threadIdx.x;  // 128
    for (int idx = t; idx < ROWS * K; idx += 128) {
        int r = idx / K, k = idx - r * K;
        int gr = r0 + r;
        xs[r][k] = (gr < n) ? X[(size_t)gr * K + k] : 0.f;
    }
    __syncthreads();
    if (t < OSTRIDE) {
        float acc[ROWS];
#pragma unroll
        for (int r = 0; r < ROWS; r++) acc[r] = 0.f;
        if (t < DOUT) {
            for (int k = 0; k < K; k++) {
                float w = W[k * DOUT + t];
#pragma unroll
                for (int r = 0; r < ROWS; r++) acc[r] += xs[r][k] * w;
            }
        }
#pragma unroll
        for (int r = 0; r < ROWS; r++) {
            int gr = r0 + r;
            if (gr < n) Y[(size_t)gr * OSTRIDE + t] = f2bf(acc[r] * dinv[gr]);
        }
    }
}

// bf16-message aggregation. msg rows = TPR uint4 chunks (8 bf16 each).
// SLOTS edges in flight per block; fp32 accumulate; LDS tree-reduce over slots.
template <int TPR, int SLOTS, int D, int RELU>
__global__ void k_agg_bf(const uint4* __restrict__ msg, const float* __restrict__ dinv,
                         const int* __restrict__ rs, const int* __restrict__ deg,
                         const int* __restrict__ csr, const float* __restrict__ bias,
                         float* __restrict__ out, int n) {
    __shared__ float red[SLOTS][TPR][8];
    int v = blockIdx.x;
    if (v >= n) return;
    int t = threadIdx.x;
    int slot = t / TPR;
    int q = t - slot * TPR;
    int start = rs[v];
    int cnt = deg[v];
    if (slot < SLOTS) {
        float acc[8] = {0.f, 0.f, 0.f, 0.f, 0.f, 0.f, 0.f, 0.f};
        for (int i = slot; i < cnt; i += SLOTS) {
            int s = csr[start + i];
            uint4 m = msg[(size_t)s * TPR + q];
            acc[0] += bf_lo(m.x); acc[1] += bf_hi(m.x);
            acc[2] += bf_lo(m.y); acc[3] += bf_hi(m.y);
            acc[4] += bf_lo(m.z); acc[5] += bf_hi(m.z);
            acc[6] += bf_lo(m.w); acc[7] += bf_hi(m.w);
        }
#pragma unroll
        for (int j = 0; j < 8; j++) red[slot][q][j] = acc[j];
    }
    __syncthreads();
#pragma unroll
    for (int sh = SLOTS / 2; sh >= 1; sh >>= 1) {
        if (slot < sh) {
#pragma unroll
            for (int j = 0; j < 8; j++) red[slot][q][j] += red[slot + sh][q][j];
        }
        __syncthreads();
    }
    if (t < TPR) {
        float dv = dinv[v];
        uint4 m = msg[(size_t)v * TPR + t];  // self-loop: msg[v] = dv*xw[v]
        float o[8];
        o[0] = red[0][t][0] + bf_lo(m.x); o[1] = red[0][t][1] + bf_hi(m.x);
        o[2] = red[0][t][2] + bf_lo(m.y); o[3] = red[0][t][3] + bf_hi(m.y);
        o[4] = red[0][t][4] + bf_lo(m.z); o[5] = red[0][t][5] + bf_hi(m.z);
        o[6] = red[0][t][6] + bf_lo(m.w); o[7] = red[0][t][7] + bf_hi(m.w);
#pragma unroll
        for (int j = 0; j < 8; j++) {
            int f = 8 * t + j;
            if (f < D) {
                float r = dv * o[j] + bias[f];
                if (RELU) r = fmaxf(r, 0.f);
                out[(size_t)v * D + f] = r;
            }
        }
    }
}

static inline size_t alignup(size_t x) { return (x + 255) & ~(size_t)255; }

extern "C" void kernel_launch(void* const* d_in, const int* in_sizes, int n_in,
                              void* d_out, int out_size, void* d_ws, size_t ws_size,
                              hipStream_t stream) {
    const float* x = (const float*)d_in[0];
    const int* edge = (const int*)d_in[1];
    const float* W1 = (const float*)d_in[2];
    const float* b1 = (const float*)d_in[3];
    const float* W2 = (const float*)d_in[4];
    const float* b2 = (const float*)d_in[5];

    const int N = in_sizes[0] / 128;
    const int E = in_sizes[1] / 2;
    const int* src = edge;
    const int* dst = edge + E;
    const int nb = (N + 255) >> BSH;  // 391 buckets for N=100000 (<= 512)

    char* w = (char*)d_ws;
    int* deg = (int*)w;              w += alignup((size_t)N * 4);
    float* dinv = (float*)w;         w += alignup((size_t)N * 4);
    int* rs = (int*)w;               w += alignup((size_t)N * 4);
    int* bhist = (int*)w;            w += alignup(4096);
    int* bbase = (int*)w;            w += alignup(4096);
    int* bwcur = (int*)w;            w += alignup(4096);
    int* csr = (int*)w;              w += alignup((size_t)E * 4);
    unsigned short* msg1 = (unsigned short*)w; w += alignup((size_t)N * 128 * 2);
    unsigned short* msg2 = (unsigned short*)w; w += alignup((size_t)N * 72 * 2);
    float* h = (float*)w;            w += alignup((size_t)N * 128 * 4);
    // tmp (packed bucket-grouped edges, E*8B) aliases h: used only before h is written.
    unsigned long long* tmp = (unsigned long long*)h;

    // ---- CSR build (bucketed counting sort) ----
    hipMemsetAsync(bhist, 0, (size_t)(nb + 1) * 4, stream);
    k_bucket_hist<<<256, 256, 0, stream>>>(dst, bhist, E, nb);
    k_bucket_scan<<<1, 512, 0, stream>>>(bhist, bbase, bwcur, nb, E);
    k_bucket_scatter<<<(E + BCHUNK - 1) / BCHUNK, 256, 0, stream>>>(src, dst, bwcur, tmp, E, nb);
    k_bucket_finalize<<<nb, 256, 0, stream>>>(tmp, bbase, deg, dinv, rs, csr, N);

    // Layer 1: msg1 = bf16(dinv * (x @ W1)) [N,128] ; agg -> h [N,128] fp32 (bias+relu)
    k_gemm_bf<8, 128, 128, 128><<<(N + 7) / 8, 128, 0, stream>>>(x, W1, dinv, msg1, N);
    k_agg_bf<16, 16, 128, 1><<<N, 256, 0, stream>>>((const uint4*)msg1, dinv, rs, deg, csr,
                                                    b1, h, N);

    // Layer 2: msg2 = bf16(dinv * (h @ W2)) [N,72 pad] ; agg -> d_out [N,70] (bias)
    k_gemm_bf<8, 128, 70, 72><<<(N + 7) / 8, 128, 0, stream>>>(h, W2, dinv, msg2, N);
    k_agg_bf<9, 16, 70, 0><<<N, 192, 0, stream>>>((const uint4*)msg2, dinv, rs, deg, csr,
                                                  b2, (float*)d_out, N);
}

// Round 5
// 441.908 us; speedup vs baseline: 1.7931x; 1.1890x over previous
//
#include <hip/hip_runtime.h>
#include <hip/hip_bf16.h>

// GCN 2-layer. msg[s] = dinv[s] * (x@W)[s] stored in bf16 (dinv folded at GEMM epilogue).
// out[v] = dinv[v] * (sum_{e:dst=v} msg[src] + msg[v]) + b ; layer1 relu.
// CSR build: bucketed 2-phase counting sort (bucket = dst>>8, W=256 nodes/bucket).
// Aggregation: one node per WAVE, cross-slot reduce via shuffles (no LDS, no barriers).

#define BSH 8           // bucket shift: 256 nodes per bucket
#define BCHUNK 8192     // edges per pass-B block

__device__ __forceinline__ float bf_lo(unsigned u) { return __uint_as_float(u << 16); }
__device__ __forceinline__ float bf_hi(unsigned u) { return __uint_as_float(u & 0xffff0000u); }
__device__ __forceinline__ unsigned short f2bf(float f) {
    unsigned u = __float_as_uint(f);
    u += 0x7fff + ((u >> 16) & 1);  // round-to-nearest-even
    return (unsigned short)(u >> 16);
}

// Bucket histogram over dst (LDS-staged).
__global__ void k_bucket_hist(const int* __restrict__ dst, int* __restrict__ bhist,
                              int E, int nb) {
    __shared__ int h[512];
    int t = threadIdx.x;
    for (int j = t; j < nb; j += blockDim.x) h[j] = 0;
    __syncthreads();
    int i = blockIdx.x * blockDim.x + t;
    int stride = gridDim.x * blockDim.x;
    for (; i < E; i += stride) atomicAdd(&h[dst[i] >> BSH], 1);
    __syncthreads();
    for (int j = t; j < nb; j += blockDim.x) {
        int c = h[j];
        if (c) atomicAdd(&bhist[j], c);
    }
}

// Exclusive scan of bucket counts (nb <= 512), one block of 512.
__global__ void k_bucket_scan(const int* __restrict__ bhist, int* __restrict__ bbase,
                              int* __restrict__ bwcur, int nb, int E) {
    __shared__ int s[512];
    int t = threadIdx.x;
    int v = (t < nb) ? bhist[t] : 0;
    s[t] = v;
    __syncthreads();
    for (int off = 1; off < 512; off <<= 1) {
        int add = (t >= off) ? s[t - off] : 0;
        __syncthreads();
        s[t] += add;
        __syncthreads();
    }
    if (t < nb) {
        int excl = s[t] - v;
        bbase[t] = excl;
        bwcur[t] = excl;
    }
    if (t == 0) bbase[nb] = E;
}

// Pass B: group edges by bucket into tmp (packed dst<<32|src), per-block runs.
__global__ void k_bucket_scatter(const int* __restrict__ src, const int* __restrict__ dst,
                                 int* __restrict__ bwcur,
                                 unsigned long long* __restrict__ tmp, int E, int nb) {
    __shared__ int lh[512];   // per-block bucket counts, then per-bucket running offset
    __shared__ int lb[512];   // per-block bucket base in tmp
    int t = threadIdx.x;
    for (int j = t; j < nb; j += 256) lh[j] = 0;
    __syncthreads();
    int e0 = blockIdx.x * BCHUNK;
    int e1 = min(E, e0 + BCHUNK);
    for (int e = e0 + t; e < e1; e += 256) atomicAdd(&lh[dst[e] >> BSH], 1);
    __syncthreads();
    for (int j = t; j < nb; j += 256) {
        int c = lh[j];
        lb[j] = c ? atomicAdd(&bwcur[j], c) : 0;
        lh[j] = 0;
    }
    __syncthreads();
    for (int e = e0 + t; e < e1; e += 256) {
        int d = dst[e];
        int b = d >> BSH;
        int o = atomicAdd(&lh[b], 1);
        tmp[lb[b] + o] = ((unsigned long long)(unsigned)d << 32) | (unsigned)src[e];
    }
}

// Pass C: one block per bucket. Per-node degree count (LDS), scan, write
// deg/dinv/rs densely, scatter csr within this bucket's window (LDS cursors).
__global__ void k_bucket_finalize(const unsigned long long* __restrict__ tmp,
                                  const int* __restrict__ bbase,
                                  int* __restrict__ deg, float* __restrict__ dinv,
                                  int* __restrict__ rs, int* __restrict__ csr, int N) {
    __shared__ int cnt[256];  // per-node count, later reused as cursor
    __shared__ int sc[256];   // scan buffer -> exclusive prefix
    int b = blockIdx.x;
    int t = threadIdx.x;
    int e0 = bbase[b], e1 = bbase[b + 1];
    cnt[t] = 0;
    __syncthreads();
    for (int e = e0 + t; e < e1; e += 256) {
        int d = (int)(tmp[e] >> 32);
        atomicAdd(&cnt[d & 255], 1);
    }
    __syncthreads();
    int c = cnt[t];
    sc[t] = c;
    __syncthreads();
    for (int off = 1; off < 256; off <<= 1) {
        int add = (t >= off) ? sc[t - off] : 0;
        __syncthreads();
        sc[t] += add;
        __syncthreads();
    }
    int excl = sc[t] - c;
    __syncthreads();
    sc[t] = excl;  // exclusive prefix, needed by all threads below
    int node = (b << BSH) + t;
    if (node < N) {
        deg[node] = c;
        dinv[node] = rsqrtf((float)(c + 1));  // +1 self-loop
        rs[node] = e0 + excl;
    }
    cnt[t] = 0;  // cursor
    __syncthreads();
    for (int e = e0 + t; e < e1; e += 256) {
        unsigned long long p = tmp[e];
        int j = ((int)(p >> 32)) & 255;
        int o = atomicAdd(&cnt[j], 1);
        csr[e0 + sc[j] + o] = (int)(p & 0xffffffffu);
    }
}

// fp32 GEMM, bf16 output scaled by dinv[row]: Y[r, t] = bf16(dinv[r] * (X@W)[r, t]).
// Columns [DOUT, OSTRIDE) zero-padded. Block = 128 threads, ROWS rows per block.
template <int ROWS, int K, int DOUT, int OSTRIDE>
__global__ void k_gemm_bf(const float* __restrict__ X, const float* __restrict__ W,
                          const float* __restrict__ dinv, unsigned short* __restrict__ Y,
                          int n) {
    __shared__ float xs[ROWS][K];
    int r0 = blockIdx.x * ROWS;
    int t = threadIdx.x;  // 128
    for (int idx = t; idx < ROWS * K; idx += 128) {
        int r = idx / K, k = idx - r * K;
        int gr = r0 + r;
        xs[r][k] = (gr < n) ? X[(size_t)gr * K + k] : 0.f;
    }
    __syncthreads();
    if (t < OSTRIDE) {
        float acc[ROWS];
#pragma unroll
        for (int r = 0; r < ROWS; r++) acc[r] = 0.f;
        if (t < DOUT) {
            for (int k = 0; k < K; k++) {
                float w = W[k * DOUT + t];
#pragma unroll
                for (int r = 0; r < ROWS; r++) acc[r] += xs[r][k] * w;
            }
        }
#pragma unroll
        for (int r = 0; r < ROWS; r++) {
            int gr = r0 + r;
            if (gr < n) Y[(size_t)gr * OSTRIDE + t] = f2bf(acc[r] * dinv[gr]);
        }
    }
}

// Layer-1 aggregation: one node per wave. 4 slots x 16 lanes; lane q holds
// features 8q..8q+7 (one uint4 = 8 bf16). Cross-slot reduce: shfl_xor 32,16.
template <int RELU>
__global__ void k_agg_w128(const uint4* __restrict__ msg, const float* __restrict__ dinv,
                           const int* __restrict__ rs, const int* __restrict__ deg,
                           const int* __restrict__ csr, const float* __restrict__ bias,
                           float* __restrict__ out, int n) {
    int lane = threadIdx.x & 63;
    int v = blockIdx.x * 4 + (threadIdx.x >> 6);
    if (v >= n) return;
    int q = lane & 15;
    int slot = lane >> 4;  // 0..3
    int start = rs[v];
    int cnt = deg[v];
    float dv = dinv[v];
    uint4 mself = msg[(size_t)v * 16 + q];  // self-loop: msg[v] = dv*xw[v]
    float acc[8] = {0.f, 0.f, 0.f, 0.f, 0.f, 0.f, 0.f, 0.f};
    for (int i = slot; i < cnt; i += 4) {
        int s = csr[start + i];
        uint4 m = msg[(size_t)s * 16 + q];
        acc[0] += bf_lo(m.x); acc[1] += bf_hi(m.x);
        acc[2] += bf_lo(m.y); acc[3] += bf_hi(m.y);
        acc[4] += bf_lo(m.z); acc[5] += bf_hi(m.z);
        acc[6] += bf_lo(m.w); acc[7] += bf_hi(m.w);
    }
#pragma unroll
    for (int j = 0; j < 8; j++) acc[j] += __shfl_xor(acc[j], 32);
#pragma unroll
    for (int j = 0; j < 8; j++) acc[j] += __shfl_xor(acc[j], 16);
    if (slot == 0) {
        float o[8];
        o[0] = acc[0] + bf_lo(mself.x); o[1] = acc[1] + bf_hi(mself.x);
        o[2] = acc[2] + bf_lo(mself.y); o[3] = acc[3] + bf_hi(mself.y);
        o[4] = acc[4] + bf_lo(mself.z); o[5] = acc[5] + bf_hi(mself.z);
        o[6] = acc[6] + bf_lo(mself.w); o[7] = acc[7] + bf_hi(mself.w);
        float r[8];
#pragma unroll
        for (int j = 0; j < 8; j++) {
            r[j] = dv * o[j] + bias[8 * q + j];
            if (RELU) r[j] = fmaxf(r[j], 0.f);
        }
        float4* op = (float4*)(out + (size_t)v * 128 + 8 * q);  // 16B-aligned (row=512B)
        op[0] = make_float4(r[0], r[1], r[2], r[3]);
        op[1] = make_float4(r[4], r[5], r[6], r[7]);
    }
}

// Layer-2 aggregation: one node per wave. msg rows = 9 uint4 (72 bf16, 70 valid).
// 7 slots x 9 lanes (lanes 0..62). Reduce: +27 (slots 0-2 += 3-5), then +54
// (slot0 += slot6) and +9/+18 (slot0 += slots1,2) — source lanes never written
// by earlier predicated adds.
__global__ void k_agg_w72(const uint4* __restrict__ msg, const float* __restrict__ dinv,
                          const int* __restrict__ rs, const int* __restrict__ deg,
                          const int* __restrict__ csr, const float* __restrict__ bias,
                          float* __restrict__ out, int n) {
    int lane = threadIdx.x & 63;
    int v = blockIdx.x * 4 + (threadIdx.x >> 6);
    if (v >= n) return;
    int slot = lane / 9;          // 0..7 (lane 63 -> 7, inactive)
    int q = lane - slot * 9;      // 0..8
    bool active = lane < 63;
    int start = rs[v];
    int cnt = deg[v];
    float dv = dinv[v];
    float acc[8] = {0.f, 0.f, 0.f, 0.f, 0.f, 0.f, 0.f, 0.f};
    uint4 mself = make_uint4(0, 0, 0, 0);
    if (active) {
        mself = msg[(size_t)v * 9 + q];
        for (int i = slot; i < cnt; i += 7) {
            int s = csr[start + i];
            uint4 m = msg[(size_t)s * 9 + q];
            acc[0] += bf_lo(m.x); acc[1] += bf_hi(m.x);
            acc[2] += bf_lo(m.y); acc[3] += bf_hi(m.y);
            acc[4] += bf_lo(m.z); acc[5] += bf_hi(m.z);
            acc[6] += bf_lo(m.w); acc[7] += bf_hi(m.w);
        }
    }
#pragma unroll
    for (int j = 0; j < 8; j++) {
        float t27 = __shfl(acc[j], lane + 27);
        if (lane < 27) acc[j] += t27;  // slots 0,1,2 += slots 3,4,5
    }
#pragma unroll
    for (int j = 0; j < 8; j++) {
        float t54 = __shfl(acc[j], lane + 54);  // slot 6
        float t9  = __shfl(acc[j], lane + 9);   // slot 1 (s1+s4)
        float t18 = __shfl(acc[j], lane + 18);  // slot 2 (s2+s5)
        if (lane < 9) acc[j] += t54 + t9 + t18;
    }
    if (lane < 9) {
        float o[8];
        o[0] = acc[0] + bf_lo(mself.x); o[1] = acc[1] + bf_hi(mself.x);
        o[2] = acc[2] + bf_lo(mself.y); o[3] = acc[3] + bf_hi(mself.y);
        o[4] = acc[4] + bf_lo(mself.z); o[5] = acc[5] + bf_hi(mself.z);
        o[6] = acc[6] + bf_lo(mself.w); o[7] = acc[7] + bf_hi(mself.w);
        float* orow = out + (size_t)v * 70 + 8 * q;
#pragma unroll
        for (int jj = 0; jj < 4; jj++) {
            int f = 8 * q + 2 * jj;
            if (f < 70) {  // rows are 8B-aligned (280B); use float2 stores
                float2 st = make_float2(dv * o[2 * jj] + bias[f],
                                        dv * o[2 * jj + 1] + bias[f + 1]);
                *(float2*)(orow + 2 * jj) = st;
            }
        }
    }
}

static inline size_t alignup(size_t x) { return (x + 255) & ~(size_t)255; }

extern "C" void kernel_launch(void* const* d_in, const int* in_sizes, int n_in,
                              void* d_out, int out_size, void* d_ws, size_t ws_size,
                              hipStream_t stream) {
    const float* x = (const float*)d_in[0];
    const int* edge = (const int*)d_in[1];
    const float* W1 = (const float*)d_in[2];
    const float* b1 = (const float*)d_in[3];
    const float* W2 = (const float*)d_in[4];
    const float* b2 = (const float*)d_in[5];

    const int N = in_sizes[0] / 128;
    const int E = in_sizes[1] / 2;
    const int* src = edge;
    const int* dst = edge + E;
    const int nb = (N + 255) >> BSH;  // 391 buckets for N=100000 (<= 512)

    char* w = (char*)d_ws;
    int* deg = (int*)w;              w += alignup((size_t)N * 4);
    float* dinv = (float*)w;         w += alignup((size_t)N * 4);
    int* rs = (int*)w;               w += alignup((size_t)N * 4);
    int* bhist = (int*)w;            w += alignup(4096);
    int* bbase = (int*)w;            w += alignup(4096);
    int* bwcur = (int*)w;            w += alignup(4096);
    int* csr = (int*)w;              w += alignup((size_t)E * 4);
    unsigned short* msg1 = (unsigned short*)w; w += alignup((size_t)N * 128 * 2);
    unsigned short* msg2 = (unsigned short*)w; w += alignup((size_t)N * 72 * 2);
    float* h = (float*)w;            w += alignup((size_t)N * 128 * 4);
    // tmp (packed bucket-grouped edges, E*8B) aliases h: used only before h is written.
    unsigned long long* tmp = (unsigned long long*)h;

    // ---- CSR build (bucketed counting sort) ----
    hipMemsetAsync(bhist, 0, (size_t)(nb + 1) * 4, stream);
    k_bucket_hist<<<256, 256, 0, stream>>>(dst, bhist, E, nb);
    k_bucket_scan<<<1, 512, 0, stream>>>(bhist, bbase, bwcur, nb, E);
    k_bucket_scatter<<<(E + BCHUNK - 1) / BCHUNK, 256, 0, stream>>>(src, dst, bwcur, tmp, E, nb);
    k_bucket_finalize<<<nb, 256, 0, stream>>>(tmp, bbase, deg, dinv, rs, csr, N);

    // Layer 1: msg1 = bf16(dinv * (x @ W1)) [N,128] ; agg -> h [N,128] fp32 (bias+relu)
    k_gemm_bf<8, 128, 128, 128><<<(N + 7) / 8, 128, 0, stream>>>(x, W1, dinv, msg1, N);
    k_agg_w128<1><<<(N + 3) / 4, 256, 0, stream>>>((const uint4*)msg1, dinv, rs, deg, csr,
                                                   b1, h, N);

    // Layer 2: msg2 = bf16(dinv * (h @ W2)) [N,72 pad] ; agg -> d_out [N,70] (bias)
    k_gemm_bf<8, 128, 70, 72><<<(N + 7) / 8, 128, 0, stream>>>(h, W2, dinv, msg2, N);
    k_agg_w72<<<(N + 3) / 4, 256, 0, stream>>>((const uint4*)msg2, dinv, rs, deg, csr,
                                               b2, (float*)d_out, N);
}

// Round 6
// 375.715 us; speedup vs baseline: 2.1090x; 1.1762x over previous
//
#include <hip/hip_runtime.h>
#include <hip/hip_bf16.h>

// GCN 2-layer. msg[s] = dinv[s] * (x@W)[s] stored in bf16 (dinv folded at GEMM epilogue).
// out[v] = dinv[v] * (sum_{e:dst=v} msg[src] + msg[v]) + b ; layer1 relu.
// CSR build: bucketed 2-phase counting sort (bucket = dst>>8).
// GEMM: MFMA 16x16x32 bf16 with 2-term split (x=xh+xl, W=Wh+Wl; 3 products) for
//   ~fp32 accuracy. Block = 64 rows; x-tile split-staged in LDS (stride 136 shorts,
//   2-way bank aliasing = free); W frags held in VGPRs per wave (ntiles {w, w+4}).
// Aggregation: one node per wave, shuffle reduce (no LDS).

#define BSH 8
#define BCHUNK 8192

typedef __attribute__((ext_vector_type(8))) short short8;
typedef __attribute__((ext_vector_type(4))) float float4v;

__device__ __forceinline__ float bf_lo(unsigned u) { return __uint_as_float(u << 16); }
__device__ __forceinline__ float bf_hi(unsigned u) { return __uint_as_float(u & 0xffff0000u); }
__device__ __forceinline__ float bf2f(unsigned short h) {
    return __uint_as_float((unsigned)h << 16);
}
__device__ __forceinline__ unsigned short f2bf(float f) {
    unsigned u = __float_as_uint(f);
    u += 0x7fff + ((u >> 16) & 1);  // round-to-nearest-even
    return (unsigned short)(u >> 16);
}

// ---------------- CSR build ----------------

__global__ void k_bucket_hist(const int* __restrict__ dst, int* __restrict__ bhist,
                              int E, int nb) {
    __shared__ int h[512];
    int t = threadIdx.x;
    for (int j = t; j < nb; j += blockDim.x) h[j] = 0;
    __syncthreads();
    int i = blockIdx.x * blockDim.x + t;
    int stride = gridDim.x * blockDim.x;
    for (; i < E; i += stride) atomicAdd(&h[dst[i] >> BSH], 1);
    __syncthreads();
    for (int j = t; j < nb; j += blockDim.x) {
        int c = h[j];
        if (c) atomicAdd(&bhist[j], c);
    }
}

__global__ void k_bucket_scan(const int* __restrict__ bhist, int* __restrict__ bbase,
                              int* __restrict__ bwcur, int nb, int E) {
    __shared__ int s[512];
    int t = threadIdx.x;
    int v = (t < nb) ? bhist[t] : 0;
    s[t] = v;
    __syncthreads();
    for (int off = 1; off < 512; off <<= 1) {
        int add = (t >= off) ? s[t - off] : 0;
        __syncthreads();
        s[t] += add;
        __syncthreads();
    }
    if (t < nb) {
        int excl = s[t] - v;
        bbase[t] = excl;
        bwcur[t] = excl;
    }
    if (t == 0) bbase[nb] = E;
}

__global__ void k_bucket_scatter(const int* __restrict__ src, const int* __restrict__ dst,
                                 int* __restrict__ bwcur,
                                 unsigned long long* __restrict__ tmp, int E, int nb) {
    __shared__ int lh[512];
    __shared__ int lb[512];
    int t = threadIdx.x;
    for (int j = t; j < nb; j += 256) lh[j] = 0;
    __syncthreads();
    int e0 = blockIdx.x * BCHUNK;
    int e1 = min(E, e0 + BCHUNK);
    for (int e = e0 + t; e < e1; e += 256) atomicAdd(&lh[dst[e] >> BSH], 1);
    __syncthreads();
    for (int j = t; j < nb; j += 256) {
        int c = lh[j];
        lb[j] = c ? atomicAdd(&bwcur[j], c) : 0;
        lh[j] = 0;
    }
    __syncthreads();
    for (int e = e0 + t; e < e1; e += 256) {
        int d = dst[e];
        int b = d >> BSH;
        int o = atomicAdd(&lh[b], 1);
        tmp[lb[b] + o] = ((unsigned long long)(unsigned)d << 32) | (unsigned)src[e];
    }
}

__global__ void k_bucket_finalize(const unsigned long long* __restrict__ tmp,
                                  const int* __restrict__ bbase,
                                  int* __restrict__ deg, float* __restrict__ dinv,
                                  int* __restrict__ rs, int* __restrict__ csr, int N) {
    __shared__ int cnt[256];
    __shared__ int sc[256];
    int b = blockIdx.x;
    int t = threadIdx.x;
    int e0 = bbase[b], e1 = bbase[b + 1];
    cnt[t] = 0;
    __syncthreads();
    for (int e = e0 + t; e < e1; e += 256) {
        int d = (int)(tmp[e] >> 32);
        atomicAdd(&cnt[d & 255], 1);
    }
    __syncthreads();
    int c = cnt[t];
    sc[t] = c;
    __syncthreads();
    for (int off = 1; off < 256; off <<= 1) {
        int add = (t >= off) ? sc[t - off] : 0;
        __syncthreads();
        sc[t] += add;
        __syncthreads();
    }
    int excl = sc[t] - c;
    __syncthreads();
    sc[t] = excl;
    int node = (b << BSH) + t;
    if (node < N) {
        deg[node] = c;
        dinv[node] = rsqrtf((float)(c + 1));
        rs[node] = e0 + excl;
    }
    cnt[t] = 0;
    __syncthreads();
    for (int e = e0 + t; e < e1; e += 256) {
        unsigned long long p = tmp[e];
        int j = ((int)(p >> 32)) & 255;
        int o = atomicAdd(&cnt[j], 1);
        csr[e0 + sc[j] + o] = (int)(p & 0xffffffffu);
    }
}

// ---------------- MFMA GEMM (split-bf16, ~fp32 accuracy) ----------------
// Y[r,c] = bf16(dinv[r] * (X@W)[r,c]); cols [DOUT, OSTRIDE) written as 0.
// Block: 256 thr = 4 waves, 64 rows. Wave handles ntiles {wave, wave+4} (< NT).
// K fixed at 128 (4 chunks of 32).
template <int DOUT, int OSTRIDE, int NT>
__global__ __launch_bounds__(256, 3) void k_gemm_mfma(
        const float* __restrict__ X, const float* __restrict__ W,
        const float* __restrict__ dinv, unsigned short* __restrict__ Y, int n) {
    __shared__ short xs_h[64][136];  // stride 136 shorts: 68 words -> 2-way banks (free)
    __shared__ short xs_l[64][136];
    int t = threadIdx.x;
    int lane = t & 63, wave = t >> 6;
    int m16 = lane & 15, quad = lane >> 4;
    int r0 = blockIdx.x * 64;

    // --- W fragments into VGPRs (pre-barrier; W is L2-resident) ---
    // B-layout: lane holds B[k=quad*8+j][n=m16] for its 16-col tile.
    short8 bh[2][4], bl[2][4];
    int nt0 = wave, nt1 = wave + 4;
#pragma unroll
    for (int i = 0; i < 2; i++) {
        int nt = i ? nt1 : nt0;
        if (nt >= NT) continue;
        int col = nt * 16 + m16;
        bool colok = col < DOUT;
#pragma unroll
        for (int kc = 0; kc < 4; kc++) {
            short8 h, l;
#pragma unroll
            for (int j = 0; j < 8; j++) {
                int k = kc * 32 + quad * 8 + j;
                float w = colok ? W[k * DOUT + col] : 0.f;
                unsigned short hb = f2bf(w);
                unsigned short lb = f2bf(w - bf2f(hb));
                h[j] = (short)hb;
                l[j] = (short)lb;
            }
            bh[i][kc] = h;
            bl[i][kc] = l;
        }
    }

    // --- stage x tile (64 rows x 128 k), split into h/l bf16 ---
    for (int p = t; p < 64 * 64; p += 256) {
        int row = p >> 6;       // 0..63
        int kk = p & 63;        // pair index, k = 2*kk
        int gr = r0 + row;
        if (gr >= n) gr = n - 1;  // clamp (stores guarded later)
        float2 xv = *(const float2*)(X + (size_t)gr * 128 + 2 * kk);
        unsigned short h0 = f2bf(xv.x), h1 = f2bf(xv.y);
        unsigned short l0 = f2bf(xv.x - bf2f(h0)), l1 = f2bf(xv.y - bf2f(h1));
        *(unsigned*)&xs_h[row][2 * kk] = (unsigned)h0 | ((unsigned)h1 << 16);
        *(unsigned*)&xs_l[row][2 * kk] = (unsigned)l0 | ((unsigned)l1 << 16);
    }
    __syncthreads();

    float4v acc[2][4];
#pragma unroll
    for (int i = 0; i < 2; i++)
#pragma unroll
        for (int ms = 0; ms < 4; ms++) acc[i][ms] = (float4v){0.f, 0.f, 0.f, 0.f};

#pragma unroll
    for (int kc = 0; kc < 4; kc++) {
#pragma unroll
        for (int ms = 0; ms < 4; ms++) {
            // A-layout: lane holds A[m=m16][k=quad*8+j] of row block ms*16.
            short8 ah = *(short8*)&xs_h[ms * 16 + m16][kc * 32 + quad * 8];
            short8 al = *(short8*)&xs_l[ms * 16 + m16][kc * 32 + quad * 8];
#pragma unroll
            for (int i = 0; i < 2; i++) {
                int nt = i ? nt1 : nt0;
                if (nt >= NT) continue;
                acc[i][ms] = __builtin_amdgcn_mfma_f32_16x16x32_bf16(ah, bh[i][kc], acc[i][ms], 0, 0, 0);
                acc[i][ms] = __builtin_amdgcn_mfma_f32_16x16x32_bf16(al, bh[i][kc], acc[i][ms], 0, 0, 0);
                acc[i][ms] = __builtin_amdgcn_mfma_f32_16x16x32_bf16(ah, bl[i][kc], acc[i][ms], 0, 0, 0);
            }
        }
    }

    // --- epilogue: D layout col=m16, row=quad*4+r ---
#pragma unroll
    for (int i = 0; i < 2; i++) {
        int nt = i ? nt1 : nt0;
        if (nt >= NT) continue;
        int col = nt * 16 + m16;
        if (col >= OSTRIDE) continue;
#pragma unroll
        for (int ms = 0; ms < 4; ms++) {
#pragma unroll
            for (int r = 0; r < 4; r++) {
                int row = r0 + ms * 16 + quad * 4 + r;
                if (row < n) {
                    float val = (col < DOUT) ? acc[i][ms][r] * dinv[row] : 0.f;
                    Y[(size_t)row * OSTRIDE + col] = f2bf(val);
                }
            }
        }
    }
}

// ---------------- Aggregation (wave per node) ----------------

template <int RELU>
__global__ void k_agg_w128(const uint4* __restrict__ msg, const float* __restrict__ dinv,
                           const int* __restrict__ rs, const int* __restrict__ deg,
                           const int* __restrict__ csr, const float* __restrict__ bias,
                           float* __restrict__ out, int n) {
    int lane = threadIdx.x & 63;
    int v = blockIdx.x * 4 + (threadIdx.x >> 6);
    if (v >= n) return;
    int q = lane & 15;
    int slot = lane >> 4;
    int start = rs[v];
    int cnt = deg[v];
    float dv = dinv[v];
    uint4 mself = msg[(size_t)v * 16 + q];
    float acc[8] = {0.f, 0.f, 0.f, 0.f, 0.f, 0.f, 0.f, 0.f};
    for (int i = slot; i < cnt; i += 4) {
        int s = csr[start + i];
        uint4 m = msg[(size_t)s * 16 + q];
        acc[0] += bf_lo(m.x); acc[1] += bf_hi(m.x);
        acc[2] += bf_lo(m.y); acc[3] += bf_hi(m.y);
        acc[4] += bf_lo(m.z); acc[5] += bf_hi(m.z);
        acc[6] += bf_lo(m.w); acc[7] += bf_hi(m.w);
    }
#pragma unroll
    for (int j = 0; j < 8; j++) acc[j] += __shfl_xor(acc[j], 32);
#pragma unroll
    for (int j = 0; j < 8; j++) acc[j] += __shfl_xor(acc[j], 16);
    if (slot == 0) {
        float o[8];
        o[0] = acc[0] + bf_lo(mself.x); o[1] = acc[1] + bf_hi(mself.x);
        o[2] = acc[2] + bf_lo(mself.y); o[3] = acc[3] + bf_hi(mself.y);
        o[4] = acc[4] + bf_lo(mself.z); o[5] = acc[5] + bf_hi(mself.z);
        o[6] = acc[6] + bf_lo(mself.w); o[7] = acc[7] + bf_hi(mself.w);
        float r[8];
#pragma unroll
        for (int j = 0; j < 8; j++) {
            r[j] = dv * o[j] + bias[8 * q + j];
            if (RELU) r[j] = fmaxf(r[j], 0.f);
        }
        float4* op = (float4*)(out + (size_t)v * 128 + 8 * q);
        op[0] = make_float4(r[0], r[1], r[2], r[3]);
        op[1] = make_float4(r[4], r[5], r[6], r[7]);
    }
}

__global__ void k_agg_w72(const uint4* __restrict__ msg, const float* __restrict__ dinv,
                          const int* __restrict__ rs, const int* __restrict__ deg,
                          const int* __restrict__ csr, const float* __restrict__ bias,
                          float* __restrict__ out, int n) {
    int lane = threadIdx.x & 63;
    int v = blockIdx.x * 4 + (threadIdx.x >> 6);
    if (v >= n) return;
    int slot = lane / 9;
    int q = lane - slot * 9;
    bool active = lane < 63;
    int start = rs[v];
    int cnt = deg[v];
    float dv = dinv[v];
    float acc[8] = {0.f, 0.f, 0.f, 0.f, 0.f, 0.f, 0.f, 0.f};
    uint4 mself = make_uint4(0, 0, 0, 0);
    if (active) {
        mself = msg[(size_t)v * 9 + q];
        for (int i = slot; i < cnt; i += 7) {
            int s = csr[start + i];
            uint4 m = msg[(size_t)s * 9 + q];
            acc[0] += bf_lo(m.x); acc[1] += bf_hi(m.x);
            acc[2] += bf_lo(m.y); acc[3] += bf_hi(m.y);
            acc[4] += bf_lo(m.z); acc[5] += bf_hi(m.z);
            acc[6] += bf_lo(m.w); acc[7] += bf_hi(m.w);
        }
    }
#pragma unroll
    for (int j = 0; j < 8; j++) {
        float t27 = __shfl(acc[j], lane + 27);
        if (lane < 27) acc[j] += t27;
    }
#pragma unroll
    for (int j = 0; j < 8; j++) {
        float t54 = __shfl(acc[j], lane + 54);
        float t9  = __shfl(acc[j], lane + 9);
        float t18 = __shfl(acc[j], lane + 18);
        if (lane < 9) acc[j] += t54 + t9 + t18;
    }
    if (lane < 9) {
        float o[8];
        o[0] = acc[0] + bf_lo(mself.x); o[1] = acc[1] + bf_hi(mself.x);
        o[2] = acc[2] + bf_lo(mself.y); o[3] = acc[3] + bf_hi(mself.y);
        o[4] = acc[4] + bf_lo(mself.z); o[5] = acc[5] + bf_hi(mself.z);
        o[6] = acc[6] + bf_lo(mself.w); o[7] = acc[7] + bf_hi(mself.w);
        float* orow = out + (size_t)v * 70 + 8 * q;
#pragma unroll
        for (int jj = 0; jj < 4; jj++) {
            int f = 8 * q + 2 * jj;
            if (f < 70) {
                float2 st = make_float2(dv * o[2 * jj] + bias[f],
                                        dv * o[2 * jj + 1] + bias[f + 1]);
                *(float2*)(orow + 2 * jj) = st;
            }
        }
    }
}

static inline size_t alignup(size_t x) { return (x + 255) & ~(size_t)255; }

extern "C" void kernel_launch(void* const* d_in, const int* in_sizes, int n_in,
                              void* d_out, int out_size, void* d_ws, size_t ws_size,
                              hipStream_t stream) {
    const float* x = (const float*)d_in[0];
    const int* edge = (const int*)d_in[1];
    const float* W1 = (const float*)d_in[2];
    const float* b1 = (const float*)d_in[3];
    const float* W2 = (const float*)d_in[4];
    const float* b2 = (const float*)d_in[5];

    const int N = in_sizes[0] / 128;
    const int E = in_sizes[1] / 2;
    const int* src = edge;
    const int* dst = edge + E;
    const int nb = (N + 255) >> BSH;

    char* w = (char*)d_ws;
    int* deg = (int*)w;              w += alignup((size_t)N * 4);
    float* dinv = (float*)w;         w += alignup((size_t)N * 4);
    int* rs = (int*)w;               w += alignup((size_t)N * 4);
    int* bhist = (int*)w;            w += alignup(4096);
    int* bbase = (int*)w;            w += alignup(4096);
    int* bwcur = (int*)w;            w += alignup(4096);
    int* csr = (int*)w;              w += alignup((size_t)E * 4);
    unsigned short* msg1 = (unsigned short*)w; w += alignup((size_t)N * 128 * 2);
    unsigned short* msg2 = (unsigned short*)w; w += alignup((size_t)N * 72 * 2);
    float* h = (float*)w;            w += alignup((size_t)N * 128 * 4);
    unsigned long long* tmp = (unsigned long long*)h;  // aliases h (disjoint in time)

    // ---- CSR build ----
    hipMemsetAsync(bhist, 0, (size_t)(nb + 1) * 4, stream);
    k_bucket_hist<<<256, 256, 0, stream>>>(dst, bhist, E, nb);
    k_bucket_scan<<<1, 512, 0, stream>>>(bhist, bbase, bwcur, nb, E);
    k_bucket_scatter<<<(E + BCHUNK - 1) / BCHUNK, 256, 0, stream>>>(src, dst, bwcur, tmp, E, nb);
    k_bucket_finalize<<<nb, 256, 0, stream>>>(tmp, bbase, deg, dinv, rs, csr, N);

    int gblocks = (N + 63) / 64;

    // Layer 1: msg1 = bf16(dinv * (x @ W1)) [N,128] ; agg -> h [N,128] fp32 (bias+relu)
    k_gemm_mfma<128, 128, 8><<<gblocks, 256, 0, stream>>>(x, W1, dinv, msg1, N);
    k_agg_w128<1><<<(N + 3) / 4, 256, 0, stream>>>((const uint4*)msg1, dinv, rs, deg, csr,
                                                   b1, h, N);

    // Layer 2: msg2 = bf16(dinv * (h @ W2)) [N,72 pad] ; agg -> d_out [N,70] (bias)
    k_gemm_mfma<70, 72, 5><<<gblocks, 256, 0, stream>>>(h, W2, dinv, msg2, N);
    k_agg_w72<<<(N + 3) / 4, 256, 0, stream>>>((const uint4*)msg2, dinv, rs, deg, csr,
                                               b2, (float*)d_out, N);
}

// Round 7
// 371.406 us; speedup vs baseline: 2.1335x; 1.0116x over previous
//
#include <hip/hip_runtime.h>
#include <hip/hip_bf16.h>

// GCN 2-layer. msg[s] = dinv[s] * (x@W)[s] stored in bf16 (dinv folded at GEMM epilogue).
// out[v] = dinv[v] * (sum_{e:dst=v} msg[src] + msg[v]) + b ; layer1 relu.
// CSR build: bucketed 2-phase counting sort (bucket = dst>>8).
// GEMM1: MFMA 16x16x32 bf16, 2-term split (~fp32 accuracy), x tile in LDS.
// FUSED agg1+GEMM2: per block, wave-per-node aggregation of 64 nodes writes h rows
//   (split bf16) straight into the GEMM LDS tile; barrier; MFMA -> msg2.
//   h never touches global memory.
// agg2: one node per wave, shuffle reduce, 2x unrolled gathers.

#define BSH 8
#define BCHUNK 8192

typedef __attribute__((ext_vector_type(8))) short short8;
typedef __attribute__((ext_vector_type(4))) float float4v;

__device__ __forceinline__ float bf_lo(unsigned u) { return __uint_as_float(u << 16); }
__device__ __forceinline__ float bf_hi(unsigned u) { return __uint_as_float(u & 0xffff0000u); }
__device__ __forceinline__ float bf2f(unsigned short h) {
    return __uint_as_float((unsigned)h << 16);
}
__device__ __forceinline__ unsigned short f2bf(float f) {
    unsigned u = __float_as_uint(f);
    u += 0x7fff + ((u >> 16) & 1);  // round-to-nearest-even
    return (unsigned short)(u >> 16);
}
__device__ __forceinline__ void acc8(float* acc, uint4 m) {
    acc[0] += bf_lo(m.x); acc[1] += bf_hi(m.x);
    acc[2] += bf_lo(m.y); acc[3] += bf_hi(m.y);
    acc[4] += bf_lo(m.z); acc[5] += bf_hi(m.z);
    acc[6] += bf_lo(m.w); acc[7] += bf_hi(m.w);
}

// ---------------- CSR build ----------------

__global__ void k_bucket_hist(const int* __restrict__ dst, int* __restrict__ bhist,
                              int E, int nb) {
    __shared__ int h[512];
    int t = threadIdx.x;
    for (int j = t; j < nb; j += blockDim.x) h[j] = 0;
    __syncthreads();
    int i = blockIdx.x * blockDim.x + t;
    int stride = gridDim.x * blockDim.x;
    for (; i < E; i += stride) atomicAdd(&h[dst[i] >> BSH], 1);
    __syncthreads();
    for (int j = t; j < nb; j += blockDim.x) {
        int c = h[j];
        if (c) atomicAdd(&bhist[j], c);
    }
}

__global__ void k_bucket_scan(const int* __restrict__ bhist, int* __restrict__ bbase,
                              int* __restrict__ bwcur, int nb, int E) {
    __shared__ int s[512];
    int t = threadIdx.x;
    int v = (t < nb) ? bhist[t] : 0;
    s[t] = v;
    __syncthreads();
    for (int off = 1; off < 512; off <<= 1) {
        int add = (t >= off) ? s[t - off] : 0;
        __syncthreads();
        s[t] += add;
        __syncthreads();
    }
    if (t < nb) {
        int excl = s[t] - v;
        bbase[t] = excl;
        bwcur[t] = excl;
    }
    if (t == 0) bbase[nb] = E;
}

__global__ void k_bucket_scatter(const int* __restrict__ src, const int* __restrict__ dst,
                                 int* __restrict__ bwcur,
                                 unsigned long long* __restrict__ tmp, int E, int nb) {
    __shared__ int lh[512];
    __shared__ int lb[512];
    int t = threadIdx.x;
    for (int j = t; j < nb; j += 256) lh[j] = 0;
    __syncthreads();
    int e0 = blockIdx.x * BCHUNK;
    int e1 = min(E, e0 + BCHUNK);
    for (int e = e0 + t; e < e1; e += 256) atomicAdd(&lh[dst[e] >> BSH], 1);
    __syncthreads();
    for (int j = t; j < nb; j += 256) {
        int c = lh[j];
        lb[j] = c ? atomicAdd(&bwcur[j], c) : 0;
        lh[j] = 0;
    }
    __syncthreads();
    for (int e = e0 + t; e < e1; e += 256) {
        int d = dst[e];
        int b = d >> BSH;
        int o = atomicAdd(&lh[b], 1);
        tmp[lb[b] + o] = ((unsigned long long)(unsigned)d << 32) | (unsigned)src[e];
    }
}

__global__ void k_bucket_finalize(const unsigned long long* __restrict__ tmp,
                                  const int* __restrict__ bbase,
                                  int* __restrict__ deg, float* __restrict__ dinv,
                                  int* __restrict__ rs, int* __restrict__ csr, int N) {
    __shared__ int cnt[256];
    __shared__ int sc[256];
    int b = blockIdx.x;
    int t = threadIdx.x;
    int e0 = bbase[b], e1 = bbase[b + 1];
    cnt[t] = 0;
    __syncthreads();
    for (int e = e0 + t; e < e1; e += 256) {
        int d = (int)(tmp[e] >> 32);
        atomicAdd(&cnt[d & 255], 1);
    }
    __syncthreads();
    int c = cnt[t];
    sc[t] = c;
    __syncthreads();
    for (int off = 1; off < 256; off <<= 1) {
        int add = (t >= off) ? sc[t - off] : 0;
        __syncthreads();
        sc[t] += add;
        __syncthreads();
    }
    int excl = sc[t] - c;
    __syncthreads();
    sc[t] = excl;
    int node = (b << BSH) + t;
    if (node < N) {
        deg[node] = c;
        dinv[node] = rsqrtf((float)(c + 1));
        rs[node] = e0 + excl;
    }
    cnt[t] = 0;
    __syncthreads();
    for (int e = e0 + t; e < e1; e += 256) {
        unsigned long long p = tmp[e];
        int j = ((int)(p >> 32)) & 255;
        int o = atomicAdd(&cnt[j], 1);
        csr[e0 + sc[j] + o] = (int)(p & 0xffffffffu);
    }
}

// ---------------- GEMM1 (MFMA, split-bf16) ----------------
// Y[r,c] = bf16(dinv[r] * (X@W)[r,c]). Block: 4 waves, 64 rows, K=128.
template <int DOUT, int OSTRIDE, int NT>
__global__ __launch_bounds__(256, 3) void k_gemm_mfma(
        const float* __restrict__ X, const float* __restrict__ W,
        const float* __restrict__ dinv, unsigned short* __restrict__ Y, int n) {
    __shared__ short xs_h[64][136];
    __shared__ short xs_l[64][136];
    int t = threadIdx.x;
    int lane = t & 63, wave = t >> 6;
    int m16 = lane & 15, quad = lane >> 4;
    int r0 = blockIdx.x * 64;

    short8 bh[2][4], bl[2][4];
    int nt0 = wave, nt1 = wave + 4;
#pragma unroll
    for (int i = 0; i < 2; i++) {
        int nt = i ? nt1 : nt0;
        if (nt >= NT) continue;
        int col = nt * 16 + m16;
        bool colok = col < DOUT;
#pragma unroll
        for (int kc = 0; kc < 4; kc++) {
            short8 h, l;
#pragma unroll
            for (int j = 0; j < 8; j++) {
                int k = kc * 32 + quad * 8 + j;
                float w = colok ? W[k * DOUT + col] : 0.f;
                unsigned short hb = f2bf(w);
                unsigned short lb = f2bf(w - bf2f(hb));
                h[j] = (short)hb;
                l[j] = (short)lb;
            }
            bh[i][kc] = h;
            bl[i][kc] = l;
        }
    }

    for (int p = t; p < 64 * 64; p += 256) {
        int row = p >> 6;
        int kk = p & 63;
        int gr = r0 + row;
        if (gr >= n) gr = n - 1;
        float2 xv = *(const float2*)(X + (size_t)gr * 128 + 2 * kk);
        unsigned short h0 = f2bf(xv.x), h1 = f2bf(xv.y);
        unsigned short l0 = f2bf(xv.x - bf2f(h0)), l1 = f2bf(xv.y - bf2f(h1));
        *(unsigned*)&xs_h[row][2 * kk] = (unsigned)h0 | ((unsigned)h1 << 16);
        *(unsigned*)&xs_l[row][2 * kk] = (unsigned)l0 | ((unsigned)l1 << 16);
    }
    __syncthreads();

    float4v acc[2][4];
#pragma unroll
    for (int i = 0; i < 2; i++)
#pragma unroll
        for (int ms = 0; ms < 4; ms++) acc[i][ms] = (float4v){0.f, 0.f, 0.f, 0.f};

#pragma unroll
    for (int kc = 0; kc < 4; kc++) {
#pragma unroll
        for (int ms = 0; ms < 4; ms++) {
            short8 ah = *(short8*)&xs_h[ms * 16 + m16][kc * 32 + quad * 8];
            short8 al = *(short8*)&xs_l[ms * 16 + m16][kc * 32 + quad * 8];
#pragma unroll
            for (int i = 0; i < 2; i++) {
                int nt = i ? nt1 : nt0;
                if (nt >= NT) continue;
                acc[i][ms] = __builtin_amdgcn_mfma_f32_16x16x32_bf16(ah, bh[i][kc], acc[i][ms], 0, 0, 0);
                acc[i][ms] = __builtin_amdgcn_mfma_f32_16x16x32_bf16(al, bh[i][kc], acc[i][ms], 0, 0, 0);
                acc[i][ms] = __builtin_amdgcn_mfma_f32_16x16x32_bf16(ah, bl[i][kc], acc[i][ms], 0, 0, 0);
            }
        }
    }

#pragma unroll
    for (int i = 0; i < 2; i++) {
        int nt = i ? nt1 : nt0;
        if (nt >= NT) continue;
        int col = nt * 16 + m16;
        if (col >= OSTRIDE) continue;
#pragma unroll
        for (int ms = 0; ms < 4; ms++) {
#pragma unroll
            for (int r = 0; r < 4; r++) {
                int row = r0 + ms * 16 + quad * 4 + r;
                if (row < n) {
                    float val = (col < DOUT) ? acc[i][ms][r] * dinv[row] : 0.f;
                    Y[(size_t)row * OSTRIDE + col] = f2bf(val);
                }
            }
        }
    }
}

// ---------------- FUSED: agg1 (wave per node) + GEMM2 (MFMA) ----------------
// Block: 4 waves, 64 nodes. Phase 1: wave w aggregates nodes r0+16w..r0+16w+15,
// h row (bias+relu) split-bf16 -> LDS tile. Phase 2: h_tile @ W2 -> msg2 (dinv-scaled).
__global__ __launch_bounds__(256, 3) void k_agg1_gemm2(
        const uint4* __restrict__ msg1, const float* __restrict__ dinv,
        const int* __restrict__ rs, const int* __restrict__ deg,
        const int* __restrict__ csr, const float* __restrict__ b1,
        const float* __restrict__ W2, unsigned short* __restrict__ msg2, int n) {
    constexpr int DOUT = 70, OSTRIDE = 72, NT = 5;
    __shared__ short xs_h[64][136];
    __shared__ short xs_l[64][136];
    int t = threadIdx.x;
    int lane = t & 63, wave = t >> 6;
    int m16 = lane & 15, quad = lane >> 4;
    int r0 = blockIdx.x * 64;

    // --- W2 fragments (pre-barrier; overlaps with phase 1 memory latency) ---
    short8 bh[2][4], bl[2][4];
    int nt0 = wave, nt1 = wave + 4;
#pragma unroll
    for (int i = 0; i < 2; i++) {
        int nt = i ? nt1 : nt0;
        if (nt >= NT) continue;
        int col = nt * 16 + m16;
        bool colok = col < DOUT;
#pragma unroll
        for (int kc = 0; kc < 4; kc++) {
            short8 h, l;
#pragma unroll
            for (int j = 0; j < 8; j++) {
                int k = kc * 32 + quad * 8 + j;
                float w = colok ? W2[k * DOUT + col] : 0.f;
                unsigned short hb = f2bf(w);
                unsigned short lb = f2bf(w - bf2f(hb));
                h[j] = (short)hb;
                l[j] = (short)lb;
            }
            bh[i][kc] = h;
            bl[i][kc] = l;
        }
    }

    // --- Phase 1: aggregate 16 nodes per wave ---
    int q = m16, slot = quad;
    float bias = b1[8 * q + 0];  // unused placeholder to keep reg layout simple
    (void)bias;
#pragma unroll 1
    for (int ni = 0; ni < 16; ni++) {
        int row = wave * 16 + ni;
        int v = r0 + row;
        if (v >= n) break;
        int start = rs[v];
        int cnt = deg[v];
        float dv = dinv[v];
        uint4 mself = msg1[(size_t)v * 16 + q];
        float acc[8] = {0.f, 0.f, 0.f, 0.f, 0.f, 0.f, 0.f, 0.f};
        int i = slot;
        for (; i + 4 < cnt; i += 8) {  // 2 gathers in flight per slot
            int s0 = csr[start + i];
            int s1 = csr[start + i + 4];
            uint4 m0 = msg1[(size_t)s0 * 16 + q];
            uint4 m1 = msg1[(size_t)s1 * 16 + q];
            acc8(acc, m0);
            acc8(acc, m1);
        }
        if (i < cnt) {
            int s = csr[start + i];
            uint4 m = msg1[(size_t)s * 16 + q];
            acc8(acc, m);
        }
#pragma unroll
        for (int j = 0; j < 8; j++) acc[j] += __shfl_xor(acc[j], 32);
#pragma unroll
        for (int j = 0; j < 8; j++) acc[j] += __shfl_xor(acc[j], 16);
        if (slot == 0) {
            float o[8];
            o[0] = acc[0] + bf_lo(mself.x); o[1] = acc[1] + bf_hi(mself.x);
            o[2] = acc[2] + bf_lo(mself.y); o[3] = acc[3] + bf_hi(mself.y);
            o[4] = acc[4] + bf_lo(mself.z); o[5] = acc[5] + bf_hi(mself.z);
            o[6] = acc[6] + bf_lo(mself.w); o[7] = acc[7] + bf_hi(mself.w);
            unsigned hw[4], lw[4];
#pragma unroll
            for (int p = 0; p < 4; p++) {
                float ra = fmaxf(dv * o[2 * p] + b1[8 * q + 2 * p], 0.f);
                float rb = fmaxf(dv * o[2 * p + 1] + b1[8 * q + 2 * p + 1], 0.f);
                unsigned short ha = f2bf(ra), hb2 = f2bf(rb);
                unsigned short la = f2bf(ra - bf2f(ha)), lb2 = f2bf(rb - bf2f(hb2));
                hw[p] = (unsigned)ha | ((unsigned)hb2 << 16);
                lw[p] = (unsigned)la | ((unsigned)lb2 << 16);
            }
            *(uint4*)&xs_h[row][8 * q] = make_uint4(hw[0], hw[1], hw[2], hw[3]);
            *(uint4*)&xs_l[row][8 * q] = make_uint4(lw[0], lw[1], lw[2], lw[3]);
        }
    }
    __syncthreads();

    // --- Phase 2: MFMA h_tile @ W2 ---
    float4v acc2[2][4];
#pragma unroll
    for (int i = 0; i < 2; i++)
#pragma unroll
        for (int ms = 0; ms < 4; ms++) acc2[i][ms] = (float4v){0.f, 0.f, 0.f, 0.f};

#pragma unroll
    for (int kc = 0; kc < 4; kc++) {
#pragma unroll
        for (int ms = 0; ms < 4; ms++) {
            short8 ah = *(short8*)&xs_h[ms * 16 + m16][kc * 32 + quad * 8];
            short8 al = *(short8*)&xs_l[ms * 16 + m16][kc * 32 + quad * 8];
#pragma unroll
            for (int i = 0; i < 2; i++) {
                int nt = i ? nt1 : nt0;
                if (nt >= NT) continue;
                acc2[i][ms] = __builtin_amdgcn_mfma_f32_16x16x32_bf16(ah, bh[i][kc], acc2[i][ms], 0, 0, 0);
                acc2[i][ms] = __builtin_amdgcn_mfma_f32_16x16x32_bf16(al, bh[i][kc], acc2[i][ms], 0, 0, 0);
                acc2[i][ms] = __builtin_amdgcn_mfma_f32_16x16x32_bf16(ah, bl[i][kc], acc2[i][ms], 0, 0, 0);
            }
        }
    }

#pragma unroll
    for (int i = 0; i < 2; i++) {
        int nt = i ? nt1 : nt0;
        if (nt >= NT) continue;
        int col = nt * 16 + m16;
        if (col >= OSTRIDE) continue;
#pragma unroll
        for (int ms = 0; ms < 4; ms++) {
#pragma unroll
            for (int r = 0; r < 4; r++) {
                int row = r0 + ms * 16 + quad * 4 + r;
                if (row < n) {
                    float val = (col < DOUT) ? acc2[i][ms][r] * dinv[row] : 0.f;
                    msg2[(size_t)row * OSTRIDE + col] = f2bf(val);
                }
            }
        }
    }
}

// ---------------- agg2 (wave per node, unrolled) ----------------
__global__ void k_agg_w72(const uint4* __restrict__ msg, const float* __restrict__ dinv,
                          const int* __restrict__ rs, const int* __restrict__ deg,
                          const int* __restrict__ csr, const float* __restrict__ bias,
                          float* __restrict__ out, int n) {
    int lane = threadIdx.x & 63;
    int v = blockIdx.x * 4 + (threadIdx.x >> 6);
    if (v >= n) return;
    int slot = lane / 9;
    int q = lane - slot * 9;
    bool active = lane < 63;
    int start = rs[v];
    int cnt = deg[v];
    float dv = dinv[v];
    float acc[8] = {0.f, 0.f, 0.f, 0.f, 0.f, 0.f, 0.f, 0.f};
    uint4 mself = make_uint4(0, 0, 0, 0);
    if (active) {
        mself = msg[(size_t)v * 9 + q];
        int i = slot;
        for (; i + 7 < cnt; i += 14) {  // 2 gathers in flight per slot
            int s0 = csr[start + i];
            int s1 = csr[start + i + 7];
            uint4 m0 = msg[(size_t)s0 * 9 + q];
            uint4 m1 = msg[(size_t)s1 * 9 + q];
            acc8(acc, m0);
            acc8(acc, m1);
        }
        if (i < cnt) {
            int s = csr[start + i];
            uint4 m = msg[(size_t)s * 9 + q];
            acc8(acc, m);
        }
    }
#pragma unroll
    for (int j = 0; j < 8; j++) {
        float t27 = __shfl(acc[j], lane + 27);
        if (lane < 27) acc[j] += t27;
    }
#pragma unroll
    for (int j = 0; j < 8; j++) {
        float t54 = __shfl(acc[j], lane + 54);
        float t9  = __shfl(acc[j], lane + 9);
        float t18 = __shfl(acc[j], lane + 18);
        if (lane < 9) acc[j] += t54 + t9 + t18;
    }
    if (lane < 9) {
        float o[8];
        o[0] = acc[0] + bf_lo(mself.x); o[1] = acc[1] + bf_hi(mself.x);
        o[2] = acc[2] + bf_lo(mself.y); o[3] = acc[3] + bf_hi(mself.y);
        o[4] = acc[4] + bf_lo(mself.z); o[5] = acc[5] + bf_hi(mself.z);
        o[6] = acc[6] + bf_lo(mself.w); o[7] = acc[7] + bf_hi(mself.w);
        float* orow = out + (size_t)v * 70 + 8 * q;
#pragma unroll
        for (int jj = 0; jj < 4; jj++) {
            int f = 8 * q + 2 * jj;
            if (f < 70) {
                float2 st = make_float2(dv * o[2 * jj] + bias[f],
                                        dv * o[2 * jj + 1] + bias[f + 1]);
                *(float2*)(orow + 2 * jj) = st;
            }
        }
    }
}

static inline size_t alignup(size_t x) { return (x + 255) & ~(size_t)255; }

extern "C" void kernel_launch(void* const* d_in, const int* in_sizes, int n_in,
                              void* d_out, int out_size, void* d_ws, size_t ws_size,
                              hipStream_t stream) {
    const float* x = (const float*)d_in[0];
    const int* edge = (const int*)d_in[1];
    const float* W1 = (const float*)d_in[2];
    const float* b1 = (const float*)d_in[3];
    const float* W2 = (const float*)d_in[4];
    const float* b2 = (const float*)d_in[5];

    const int N = in_sizes[0] / 128;
    const int E = in_sizes[1] / 2;
    const int* src = edge;
    const int* dst = edge + E;
    const int nb = (N + 255) >> BSH;

    char* w = (char*)d_ws;
    int* deg = (int*)w;              w += alignup((size_t)N * 4);
    float* dinv = (float*)w;         w += alignup((size_t)N * 4);
    int* rs = (int*)w;               w += alignup((size_t)N * 4);
    int* bhist = (int*)w;            w += alignup(4096);
    int* bbase = (int*)w;            w += alignup(4096);
    int* bwcur = (int*)w;            w += alignup(4096);
    int* csr = (int*)w;              w += alignup((size_t)E * 4);
    unsigned short* msg1 = (unsigned short*)w; w += alignup((size_t)N * 128 * 2);
    unsigned short* msg2 = (unsigned short*)w; w += alignup((size_t)N * 72 * 2);
    unsigned long long* tmp = (unsigned long long*)w; w += alignup((size_t)E * 8);

    // ---- CSR build ----
    hipMemsetAsync(bhist, 0, (size_t)(nb + 1) * 4, stream);
    k_bucket_hist<<<256, 256, 0, stream>>>(dst, bhist, E, nb);
    k_bucket_scan<<<1, 512, 0, stream>>>(bhist, bbase, bwcur, nb, E);
    k_bucket_scatter<<<(E + BCHUNK - 1) / BCHUNK, 256, 0, stream>>>(src, dst, bwcur, tmp, E, nb);
    k_bucket_finalize<<<nb, 256, 0, stream>>>(tmp, bbase, deg, dinv, rs, csr, N);

    int gblocks = (N + 63) / 64;

    // Layer 1 GEMM: msg1 = bf16(dinv * (x @ W1)) [N,128]
    k_gemm_mfma<128, 128, 8><<<gblocks, 256, 0, stream>>>(x, W1, dinv, msg1, N);

    // FUSED: agg1 (bias+relu) -> LDS h tile -> GEMM2 -> msg2 [N,72]
    k_agg1_gemm2<<<gblocks, 256, 0, stream>>>((const uint4*)msg1, dinv, rs, deg, csr,
                                              b1, W2, msg2, N);

    // agg2: msg2 -> d_out [N,70] (bias, no relu)
    k_agg_w72<<<(N + 3) / 4, 256, 0, stream>>>((const uint4*)msg2, dinv, rs, deg, csr,
                                               b2, (float*)d_out, N);
}

// Round 8
// 365.437 us; speedup vs baseline: 2.1683x; 1.0163x over previous
//
#include <hip/hip_runtime.h>
#include <hip/hip_bf16.h>

// GCN 2-layer. msg[s] = dinv[s] * (x@W)[s] stored in bf16 (dinv folded at GEMM epilogue).
// out[v] = dinv[v] * (sum_{e:dst=v} msg[src] + msg[v]) + b ; layer1 relu.
// CSR build: bucketed 2-phase counting sort (bucket = dst>>8).
// W pre-split once per launch into transposed bf16 hi/lo [col][k] -> GEMM B-frags are
//   single 16B loads (no per-block f2bf).
// GEMMs: MFMA 16x16x32 bf16, 2-term split (~fp32 accuracy), x tile in LDS.
// Aggregation: persistent grid-stride, one node per wave, 4 slots x 2-unroll gathers,
//   shuffle reduce, __launch_bounds__(256,8) for max occupancy. (R7 lesson: never fuse
//   the latency-bound gather into an LDS-heavy MFMA kernel - occupancy collapses.)

#define BSH 8
#define BCHUNK 8192

typedef __attribute__((ext_vector_type(8))) short short8;
typedef __attribute__((ext_vector_type(4))) float float4v;

__device__ __forceinline__ float bf_lo(unsigned u) { return __uint_as_float(u << 16); }
__device__ __forceinline__ float bf_hi(unsigned u) { return __uint_as_float(u & 0xffff0000u); }
__device__ __forceinline__ float bf2f(unsigned short h) {
    return __uint_as_float((unsigned)h << 16);
}
__device__ __forceinline__ unsigned short f2bf(float f) {
    unsigned u = __float_as_uint(f);
    u += 0x7fff + ((u >> 16) & 1);  // round-to-nearest-even
    return (unsigned short)(u >> 16);
}
__device__ __forceinline__ void acc8(float* acc, uint4 m) {
    acc[0] += bf_lo(m.x); acc[1] += bf_hi(m.x);
    acc[2] += bf_lo(m.y); acc[3] += bf_hi(m.y);
    acc[4] += bf_lo(m.z); acc[5] += bf_hi(m.z);
    acc[6] += bf_lo(m.w); acc[7] += bf_hi(m.w);
}

// ---------------- CSR build ----------------

__global__ void k_bucket_hist(const int* __restrict__ dst, int* __restrict__ bhist,
                              int E, int nb) {
    __shared__ int h[512];
    int t = threadIdx.x;
    for (int j = t; j < nb; j += blockDim.x) h[j] = 0;
    __syncthreads();
    int i = blockIdx.x * blockDim.x + t;
    int stride = gridDim.x * blockDim.x;
    for (; i < E; i += stride) atomicAdd(&h[dst[i] >> BSH], 1);
    __syncthreads();
    for (int j = t; j < nb; j += blockDim.x) {
        int c = h[j];
        if (c) atomicAdd(&bhist[j], c);
    }
}

__global__ void k_bucket_scan(const int* __restrict__ bhist, int* __restrict__ bbase,
                              int* __restrict__ bwcur, int nb, int E) {
    __shared__ int s[512];
    int t = threadIdx.x;
    int v = (t < nb) ? bhist[t] : 0;
    s[t] = v;
    __syncthreads();
    for (int off = 1; off < 512; off <<= 1) {
        int add = (t >= off) ? s[t - off] : 0;
        __syncthreads();
        s[t] += add;
        __syncthreads();
    }
    if (t < nb) {
        int excl = s[t] - v;
        bbase[t] = excl;
        bwcur[t] = excl;
    }
    if (t == 0) bbase[nb] = E;
}

__global__ void k_bucket_scatter(const int* __restrict__ src, const int* __restrict__ dst,
                                 int* __restrict__ bwcur,
                                 unsigned long long* __restrict__ tmp, int E, int nb) {
    __shared__ int lh[512];
    __shared__ int lb[512];
    int t = threadIdx.x;
    for (int j = t; j < nb; j += 256) lh[j] = 0;
    __syncthreads();
    int e0 = blockIdx.x * BCHUNK;
    int e1 = min(E, e0 + BCHUNK);
    for (int e = e0 + t; e < e1; e += 256) atomicAdd(&lh[dst[e] >> BSH], 1);
    __syncthreads();
    for (int j = t; j < nb; j += 256) {
        int c = lh[j];
        lb[j] = c ? atomicAdd(&bwcur[j], c) : 0;
        lh[j] = 0;
    }
    __syncthreads();
    for (int e = e0 + t; e < e1; e += 256) {
        int d = dst[e];
        int b = d >> BSH;
        int o = atomicAdd(&lh[b], 1);
        tmp[lb[b] + o] = ((unsigned long long)(unsigned)d << 32) | (unsigned)src[e];
    }
}

__global__ void k_bucket_finalize(const unsigned long long* __restrict__ tmp,
                                  const int* __restrict__ bbase,
                                  int* __restrict__ deg, float* __restrict__ dinv,
                                  int* __restrict__ rs, int* __restrict__ csr, int N) {
    __shared__ int cnt[256];
    __shared__ int sc[256];
    int b = blockIdx.x;
    int t = threadIdx.x;
    int e0 = bbase[b], e1 = bbase[b + 1];
    cnt[t] = 0;
    __syncthreads();
    for (int e = e0 + t; e < e1; e += 256) {
        int d = (int)(tmp[e] >> 32);
        atomicAdd(&cnt[d & 255], 1);
    }
    __syncthreads();
    int c = cnt[t];
    sc[t] = c;
    __syncthreads();
    for (int off = 1; off < 256; off <<= 1) {
        int add = (t >= off) ? sc[t - off] : 0;
        __syncthreads();
        sc[t] += add;
        __syncthreads();
    }
    int excl = sc[t] - c;
    __syncthreads();
    sc[t] = excl;
    int node = (b << BSH) + t;
    if (node < N) {
        deg[node] = c;
        dinv[node] = rsqrtf((float)(c + 1));
        rs[node] = e0 + excl;
    }
    cnt[t] = 0;
    __syncthreads();
    for (int e = e0 + t; e < e1; e += 256) {
        unsigned long long p = tmp[e];
        int j = ((int)(p >> 32)) & 255;
        int o = atomicAdd(&cnt[j], 1);
        csr[e0 + sc[j] + o] = (int)(p & 0xffffffffu);
    }
}

// ---------------- W pre-split: Wt_h/Wt_l[col][k] bf16, cols >= DOUT zeroed ----------------
__global__ void k_prep_w(const float* __restrict__ W, unsigned short* __restrict__ Wth,
                         unsigned short* __restrict__ Wtl, int DOUT, int COLS) {
    int i = blockIdx.x * blockDim.x + threadIdx.x;
    if (i >= COLS * 128) return;
    int col = i % COLS;
    int k = i / COLS;
    float w = (col < DOUT) ? W[k * DOUT + col] : 0.f;
    unsigned short h = f2bf(w);
    Wth[(size_t)col * 128 + k] = h;
    Wtl[(size_t)col * 128 + k] = f2bf(w - bf2f(h));
}

// ---------------- MFMA GEMM (split-bf16, ~fp32 accuracy) ----------------
// Y[r,c] = bf16(dinv[r] * (X@W)[r,c]). Block: 4 waves, 64 rows, K=128.
// B frags loaded as 16B vectors from pre-split Wt (no conversion).
template <int DOUT, int OSTRIDE, int NT>
__global__ __launch_bounds__(256, 3) void k_gemm_mfma(
        const float* __restrict__ X, const unsigned short* __restrict__ Wth,
        const unsigned short* __restrict__ Wtl,
        const float* __restrict__ dinv, unsigned short* __restrict__ Y, int n) {
    __shared__ short xs_h[64][136];
    __shared__ short xs_l[64][136];
    int t = threadIdx.x;
    int lane = t & 63, wave = t >> 6;
    int m16 = lane & 15, quad = lane >> 4;
    int r0 = blockIdx.x * 64;

    short8 bh[2][4], bl[2][4];
    int nt0 = wave, nt1 = wave + 4;
#pragma unroll
    for (int i = 0; i < 2; i++) {
        int nt = i ? nt1 : nt0;
        if (nt >= NT) continue;
        int col = nt * 16 + m16;  // < NT*16 <= COLS (Wt padded)
#pragma unroll
        for (int kc = 0; kc < 4; kc++) {
            bh[i][kc] = *(const short8*)&Wth[(size_t)col * 128 + kc * 32 + quad * 8];
            bl[i][kc] = *(const short8*)&Wtl[(size_t)col * 128 + kc * 32 + quad * 8];
        }
    }

    for (int p = t; p < 64 * 64; p += 256) {
        int row = p >> 6;
        int kk = p & 63;
        int gr = r0 + row;
        if (gr >= n) gr = n - 1;
        float2 xv = *(const float2*)(X + (size_t)gr * 128 + 2 * kk);
        unsigned short h0 = f2bf(xv.x), h1 = f2bf(xv.y);
        unsigned short l0 = f2bf(xv.x - bf2f(h0)), l1 = f2bf(xv.y - bf2f(h1));
        *(unsigned*)&xs_h[row][2 * kk] = (unsigned)h0 | ((unsigned)h1 << 16);
        *(unsigned*)&xs_l[row][2 * kk] = (unsigned)l0 | ((unsigned)l1 << 16);
    }
    __syncthreads();

    float4v acc[2][4];
#pragma unroll
    for (int i = 0; i < 2; i++)
#pragma unroll
        for (int ms = 0; ms < 4; ms++) acc[i][ms] = (float4v){0.f, 0.f, 0.f, 0.f};

#pragma unroll
    for (int kc = 0; kc < 4; kc++) {
#pragma unroll
        for (int ms = 0; ms < 4; ms++) {
            short8 ah = *(short8*)&xs_h[ms * 16 + m16][kc * 32 + quad * 8];
            short8 al = *(short8*)&xs_l[ms * 16 + m16][kc * 32 + quad * 8];
#pragma unroll
            for (int i = 0; i < 2; i++) {
                int nt = i ? nt1 : nt0;
                if (nt >= NT) continue;
                acc[i][ms] = __builtin_amdgcn_mfma_f32_16x16x32_bf16(ah, bh[i][kc], acc[i][ms], 0, 0, 0);
                acc[i][ms] = __builtin_amdgcn_mfma_f32_16x16x32_bf16(al, bh[i][kc], acc[i][ms], 0, 0, 0);
                acc[i][ms] = __builtin_amdgcn_mfma_f32_16x16x32_bf16(ah, bl[i][kc], acc[i][ms], 0, 0, 0);
            }
        }
    }

#pragma unroll
    for (int i = 0; i < 2; i++) {
        int nt = i ? nt1 : nt0;
        if (nt >= NT) continue;
        int col = nt * 16 + m16;
        if (col >= OSTRIDE) continue;
#pragma unroll
        for (int ms = 0; ms < 4; ms++) {
#pragma unroll
            for (int r = 0; r < 4; r++) {
                int row = r0 + ms * 16 + quad * 4 + r;
                if (row < n) {
                    float val = (col < DOUT) ? acc[i][ms][r] * dinv[row] : 0.f;
                    Y[(size_t)row * OSTRIDE + col] = f2bf(val);
                }
            }
        }
    }
}

// ---------------- agg1: persistent, one node per wave, 4 slots x 2-unroll ----------------
__global__ __launch_bounds__(256, 8) void k_agg_w128(
        const uint4* __restrict__ msg, const float* __restrict__ dinv,
        const int* __restrict__ rs, const int* __restrict__ deg,
        const int* __restrict__ csr, const float* __restrict__ bias,
        float* __restrict__ out, int n) {
    int lane = threadIdx.x & 63;
    int q = lane & 15;
    int slot = lane >> 4;
    int wid = blockIdx.x * 4 + (threadIdx.x >> 6);
    int nw = gridDim.x * 4;
    for (int v = wid; v < n; v += nw) {
        int start = rs[v];
        int cnt = deg[v];
        float dv = dinv[v];
        uint4 mself = msg[(size_t)v * 16 + q];
        float acc[8] = {0.f, 0.f, 0.f, 0.f, 0.f, 0.f, 0.f, 0.f};
        int i = slot;
        for (; i + 4 < cnt; i += 8) {  // 2 gathers in flight per slot
            int s0 = csr[start + i];
            int s1 = csr[start + i + 4];
            uint4 m0 = msg[(size_t)s0 * 16 + q];
            uint4 m1 = msg[(size_t)s1 * 16 + q];
            acc8(acc, m0);
            acc8(acc, m1);
        }
        if (i < cnt) {
            int s = csr[start + i];
            uint4 m = msg[(size_t)s * 16 + q];
            acc8(acc, m);
        }
#pragma unroll
        for (int j = 0; j < 8; j++) acc[j] += __shfl_xor(acc[j], 32);
#pragma unroll
        for (int j = 0; j < 8; j++) acc[j] += __shfl_xor(acc[j], 16);
        if (slot == 0) {
            float o[8];
            o[0] = acc[0] + bf_lo(mself.x); o[1] = acc[1] + bf_hi(mself.x);
            o[2] = acc[2] + bf_lo(mself.y); o[3] = acc[3] + bf_hi(mself.y);
            o[4] = acc[4] + bf_lo(mself.z); o[5] = acc[5] + bf_hi(mself.z);
            o[6] = acc[6] + bf_lo(mself.w); o[7] = acc[7] + bf_hi(mself.w);
            float r[8];
#pragma unroll
            for (int j = 0; j < 8; j++) r[j] = fmaxf(dv * o[j] + bias[8 * q + j], 0.f);
            float4* op = (float4*)(out + (size_t)v * 128 + 8 * q);
            op[0] = make_float4(r[0], r[1], r[2], r[3]);
            op[1] = make_float4(r[4], r[5], r[6], r[7]);
        }
    }
}

// ---------------- agg2: persistent, one node per wave, 7 slots x 9 lanes, 2-unroll ----------------
__global__ __launch_bounds__(256, 8) void k_agg_w72(
        const uint4* __restrict__ msg, const float* __restrict__ dinv,
        const int* __restrict__ rs, const int* __restrict__ deg,
        const int* __restrict__ csr, const float* __restrict__ bias,
        float* __restrict__ out, int n) {
    int lane = threadIdx.x & 63;
    int slot = lane / 9;
    int q = lane - slot * 9;
    bool active = lane < 63;
    int wid = blockIdx.x * 4 + (threadIdx.x >> 6);
    int nw = gridDim.x * 4;
    for (int v = wid; v < n; v += nw) {
        int start = rs[v];
        int cnt = deg[v];
        float dv = dinv[v];
        float acc[8] = {0.f, 0.f, 0.f, 0.f, 0.f, 0.f, 0.f, 0.f};
        uint4 mself = make_uint4(0, 0, 0, 0);
        if (active) {
            mself = msg[(size_t)v * 9 + q];
            int i = slot;
            for (; i + 7 < cnt; i += 14) {
                int s0 = csr[start + i];
                int s1 = csr[start + i + 7];
                uint4 m0 = msg[(size_t)s0 * 9 + q];
                uint4 m1 = msg[(size_t)s1 * 9 + q];
                acc8(acc, m0);
                acc8(acc, m1);
            }
            if (i < cnt) {
                int s = csr[start + i];
                uint4 m = msg[(size_t)s * 9 + q];
                acc8(acc, m);
            }
        }
#pragma unroll
        for (int j = 0; j < 8; j++) {
            float t27 = __shfl(acc[j], lane + 27);
            if (lane < 27) acc[j] += t27;
        }
#pragma unroll
        for (int j = 0; j < 8; j++) {
            float t54 = __shfl(acc[j], lane + 54);
            float t9  = __shfl(acc[j], lane + 9);
            float t18 = __shfl(acc[j], lane + 18);
            if (lane < 9) acc[j] += t54 + t9 + t18;
        }
        if (lane < 9) {
            float o[8];
            o[0] = acc[0] + bf_lo(mself.x); o[1] = acc[1] + bf_hi(mself.x);
            o[2] = acc[2] + bf_lo(mself.y); o[3] = acc[3] + bf_hi(mself.y);
            o[4] = acc[4] + bf_lo(mself.z); o[5] = acc[5] + bf_hi(mself.z);
            o[6] = acc[6] + bf_lo(mself.w); o[7] = acc[7] + bf_hi(mself.w);
            float* orow = out + (size_t)v * 70 + 8 * q;
#pragma unroll
            for (int jj = 0; jj < 4; jj++) {
                int f = 8 * q + 2 * jj;
                if (f < 70) {
                    float2 st = make_float2(dv * o[2 * jj] + bias[f],
                                            dv * o[2 * jj + 1] + bias[f + 1]);
                    *(float2*)(orow + 2 * jj) = st;
                }
            }
        }
    }
}

static inline size_t alignup(size_t x) { return (x + 255) & ~(size_t)255; }

extern "C" void kernel_launch(void* const* d_in, const int* in_sizes, int n_in,
                              void* d_out, int out_size, void* d_ws, size_t ws_size,
                              hipStream_t stream) {
    const float* x = (const float*)d_in[0];
    const int* edge = (const int*)d_in[1];
    const float* W1 = (const float*)d_in[2];
    const float* b1 = (const float*)d_in[3];
    const float* W2 = (const float*)d_in[4];
    const float* b2 = (const float*)d_in[5];

    const int N = in_sizes[0] / 128;
    const int E = in_sizes[1] / 2;
    const int* src = edge;
    const int* dst = edge + E;
    const int nb = (N + 255) >> BSH;

    char* w = (char*)d_ws;
    int* deg = (int*)w;              w += alignup((size_t)N * 4);
    float* dinv = (float*)w;         w += alignup((size_t)N * 4);
    int* rs = (int*)w;               w += alignup((size_t)N * 4);
    int* bhist = (int*)w;            w += alignup(4096);
    int* bbase = (int*)w;            w += alignup(4096);
    int* bwcur = (int*)w;            w += alignup(4096);
    int* csr = (int*)w;              w += alignup((size_t)E * 4);
    unsigned short* msg1 = (unsigned short*)w; w += alignup((size_t)N * 128 * 2);
    unsigned short* msg2 = (unsigned short*)w; w += alignup((size_t)N * 72 * 2);
    unsigned short* w1th = (unsigned short*)w; w += alignup(128 * 128 * 2);
    unsigned short* w1tl = (unsigned short*)w; w += alignup(128 * 128 * 2);
    unsigned short* w2th = (unsigned short*)w; w += alignup(80 * 128 * 2);
    unsigned short* w2tl = (unsigned short*)w; w += alignup(80 * 128 * 2);
    float* h = (float*)w;            w += alignup((size_t)N * 128 * 4);
    unsigned long long* tmp = (unsigned long long*)h;  // aliases h (disjoint in time)

    // ---- W pre-split (independent of graph) ----
    k_prep_w<<<(128 * 128 + 255) / 256, 256, 0, stream>>>(W1, w1th, w1tl, 128, 128);
    k_prep_w<<<(80 * 128 + 255) / 256, 256, 0, stream>>>(W2, w2th, w2tl, 70, 80);

    // ---- CSR build ----
    hipMemsetAsync(bhist, 0, (size_t)(nb + 1) * 4, stream);
    k_bucket_hist<<<256, 256, 0, stream>>>(dst, bhist, E, nb);
    k_bucket_scan<<<1, 512, 0, stream>>>(bhist, bbase, bwcur, nb, E);
    k_bucket_scatter<<<(E + BCHUNK - 1) / BCHUNK, 256, 0, stream>>>(src, dst, bwcur, tmp, E, nb);
    k_bucket_finalize<<<nb, 256, 0, stream>>>(tmp, bbase, deg, dinv, rs, csr, N);

    int gblocks = (N + 63) / 64;

    // Layer 1: msg1 = bf16(dinv * (x @ W1)) [N,128] ; agg -> h [N,128] fp32 (bias+relu)
    k_gemm_mfma<128, 128, 8><<<gblocks, 256, 0, stream>>>(x, w1th, w1tl, dinv, msg1, N);
    k_agg_w128<<<2048, 256, 0, stream>>>((const uint4*)msg1, dinv, rs, deg, csr, b1, h, N);

    // Layer 2: msg2 = bf16(dinv * (h @ W2)) [N,72 pad] ; agg -> d_out [N,70] (bias)
    k_gemm_mfma<70, 72, 5><<<gblocks, 256, 0, stream>>>(h, w2th, w2tl, dinv, msg2, N);
    k_agg_w72<<<2048, 256, 0, stream>>>((const uint4*)msg2, dinv, rs, deg, csr, b2,
                                        (float*)d_out, N);
}